// Round 2
// baseline (338.256 us; speedup 1.0000x reference)
//
#include <hip/hip_runtime.h>

#define D_IN  256
#define D_HID 512
#define NEG_SLOPE 0.2f
#define SCAN_CHUNK 2048
#define GATHER_BLOCKS 2048            // 8192 waves = 32/CU on 256 CUs

typedef __attribute__((ext_vector_type(8))) short short8;
typedef __attribute__((ext_vector_type(4))) float floatx4;

__device__ __forceinline__ unsigned short f2bf(float f) {
    unsigned int u = __float_as_uint(f);
    u += 0x7fffu + ((u >> 16) & 1u);   // round-to-nearest-even
    return (unsigned short)(u >> 16);
}
__device__ __forceinline__ float bf2f(unsigned short u) {
    return __uint_as_float(((unsigned int)u) << 16);
}

__device__ __forceinline__ int eidx(const void* ei, long pos, int is64) {
    return is64 ? (int)((const long long*)ei)[pos] : ((const int*)ei)[pos];
}

// ---- init: zero deg, dtype detect (block 0), out = b_out ----
__global__ __launch_bounds__(256) void k_init(int* __restrict__ deg, int N,
                                              const unsigned int* __restrict__ ei,
                                              int npairs, int* flag,
                                              const float* __restrict__ b_out,
                                              float* __restrict__ out) {
    int t = blockIdx.x * blockDim.x + threadIdx.x;
    if (blockIdx.x == 0) {
        __shared__ int nz;
        if (threadIdx.x == 0) nz = 0;
        __syncthreads();
        for (int p = threadIdx.x; p < npairs; p += blockDim.x)
            if (ei[2 * p + 1] != 0) nz = 1;
        __syncthreads();
        if (threadIdx.x == 0) *flag = nz ? 0 : 1;   // 1 => int64
    }
    if (t < N) { deg[t] = 0; out[t] = b_out[0]; }   // gemm2f atomically adds on top
}

// ---- LDS-tiled weight transpose: f32 [K,N] -> bf16 [N,K], coalesced both ways ----
// blocks 0..31:  W_gcn [256,512] -> Wgt [512,256]   (4 x 8 tiles of 64x64)
// blocks 32..95: W2    [512,512] -> W2t [512,512]   (8 x 8 tiles)
__global__ __launch_bounds__(256) void k_wtrans(const float* __restrict__ Wa,
                                                unsigned short* __restrict__ Wat,
                                                const float* __restrict__ Wb,
                                                unsigned short* __restrict__ Wbt) {
    __shared__ float t[64][65];
    int b = blockIdx.x;
    const float* W; unsigned short* Wt; int K, Nc, tk, tn;
    if (b < 32) { W = Wa; Wt = Wat; K = 256; Nc = 512; tk = b & 3; tn = b >> 2; }
    else { b -= 32; W = Wb; Wt = Wbt; K = 512; Nc = 512; tk = b & 7; tn = b >> 3; }
    int k0 = tk * 64, n0 = tn * 64;
    int c = threadIdx.x & 63;
    int r0 = threadIdx.x >> 6;
#pragma unroll
    for (int i = 0; i < 16; ++i) {
        int r = r0 + i * 4;                         // k direction
        t[r][c] = W[(long)(k0 + r) * Nc + n0 + c];  // 256B coalesced rows
    }
    __syncthreads();
#pragma unroll
    for (int i = 0; i < 16; ++i) {
        int r = r0 + i * 4;                         // n direction
        Wt[(long)(n0 + r) * K + k0 + c] = f2bf(t[c][r]);
    }
}

// ---- degree count (int only) ----
__global__ void k_deg_count(const void* __restrict__ ei, const int* __restrict__ flag,
                            int* __restrict__ deg, int E) {
    int e = blockIdx.x * blockDim.x + threadIdx.x;
    if (e < E) atomicAdd(&deg[eidx(ei, (long)E + e, *flag)], 1);
}

// ---- scan phase 1: per-chunk sums ----
__global__ __launch_bounds__(256) void k_scan1(const int* __restrict__ deg,
                                               int* __restrict__ bsum, int N) {
    int base = blockIdx.x * SCAN_CHUNK;
    int hi = min(base + SCAN_CHUNK, N);
    int s = 0;
    for (int i = base + threadIdx.x; i < hi; i += 256) s += deg[i];
#pragma unroll
    for (int off = 32; off > 0; off >>= 1) s += __shfl_down(s, off, 64);
    __shared__ int lds[4];
    if ((threadIdx.x & 63) == 0) lds[threadIdx.x >> 6] = s;
    __syncthreads();
    if (threadIdx.x == 0) bsum[blockIdx.x] = lds[0] + lds[1] + lds[2] + lds[3];
}

// ---- scan phases 2+3 merged ----
__global__ __launch_bounds__(256) void k_scan23(const int* __restrict__ deg,
                                                const int* __restrict__ bsum, int NB,
                                                int* __restrict__ offs,
                                                int* __restrict__ cursor,
                                                float* __restrict__ dinv, int N) {
    __shared__ int lds[256];
    int t = threadIdx.x;
    int bbase = 0;
    for (int i = 0; i < NB; ++i) bbase += (i < blockIdx.x) ? bsum[i] : 0;
    if (blockIdx.x == NB - 1 && t == 0) offs[N] = bbase + bsum[NB - 1];
    int base = blockIdx.x * SCAN_CHUNK;
    int lo = base + t * 8;
    int v[8], s = 0;
#pragma unroll
    for (int j = 0; j < 8; ++j) {
        int i = lo + j;
        v[j] = (i < N) ? deg[i] : 0;
        s += v[j];
    }
    lds[t] = s;
    __syncthreads();
    for (int d = 1; d < 256; d <<= 1) {
        int add = (t >= d) ? lds[t - d] : 0;
        __syncthreads();
        lds[t] += add;
        __syncthreads();
    }
    int run = bbase + ((t > 0) ? lds[t - 1] : 0);
#pragma unroll
    for (int j = 0; j < 8; ++j) {
        int i = lo + j;
        if (i < N) {
            offs[i] = run; cursor[i] = run;
            dinv[i] = rsqrtf(1.0f + (float)v[j]);
            run += v[j];
        }
    }
}

// ---- prescale: xb[i] = bf16(dinv[i] * x[i]) (folds src-side norm into features) ----
__global__ __launch_bounds__(256) void k_prescale(const float* __restrict__ x,
                                                  const float* __restrict__ dinv,
                                                  unsigned short* __restrict__ xb, int N) {
    long t = (long)blockIdx.x * blockDim.x + threadIdx.x;   // 1 thread = 4 floats
    long total = (long)N * D_IN / 4;
    if (t >= total) return;
    int row = (int)(t >> 6);                                // 64 float4 per row
    float s = dinv[row];
    float4 v = *(const float4*)(x + t * 4);
    ushort4 o;
    o.x = f2bf(v.x * s); o.y = f2bf(v.y * s); o.z = f2bf(v.z * s); o.w = f2bf(v.w * s);
    *(ushort4*)(xb + t * 4) = o;
}

// ---- fill CSR edge list (src per slot, dst-sorted) ----
__global__ void k_fill(const void* __restrict__ ei, const int* __restrict__ flag,
                       int* __restrict__ cursor, int* __restrict__ esrc, int E) {
    int e = blockIdx.x * blockDim.x + threadIdx.x;
    if (e >= E) return;
    int is64 = *flag;
    int s = eidx(ei, e, is64), d = eidx(ei, (long)E + e, is64);
    int pos = atomicAdd(&cursor[d], 1);
    esrc[pos] = s;
}

// ---- gather: persistent waves, contiguous node chunk per wave, header prefetch ----
// 8192 waves total (32/CU resident in one shot). Each wave owns nodes
// [wid*N/nw, (wid+1)*N/nw): offs/esrc walk sequentially, next node's header
// (offs end, dinv, self row) is loaded before the current edge loop so its
// latency hides under edge work.
__global__ __launch_bounds__(256) void k_gather(const unsigned short* __restrict__ xb,
                                                const int* __restrict__ offs,
                                                const int* __restrict__ esrc,
                                                const float* __restrict__ dinv,
                                                unsigned short* __restrict__ aggb,
                                                int N, int nwaves) {
    int wid = blockIdx.x * 4 + (threadIdx.x >> 6);
    int lo = (int)((long)wid * N / nwaves);
    int hi = (int)((long)(wid + 1) * N / nwaves);
    if (lo >= hi) return;
    int lane = threadIdx.x & 63;
    int half = lane >> 5;
    int colofs = (lane & 31) * 8;
    const unsigned short* xbc = xb + colofs;

    int node = lo;
    int bg = offs[node];
    int en = offs[node + 1];
    float di = dinv[node];
    short8 sv = *(const short8*)(xbc + (long)node * D_IN);   // already dinv[node]*x

    while (true) {
        int nxt = node + 1;
        bool has = nxt < hi;
        int en2 = 0; float di2 = 0.f; short8 sv2;
        if (has) {                       // next header: independent, issues early
            en2 = offs[nxt + 1];         // offs[nxt] == en (contiguous)
            di2 = dinv[nxt];
            sv2 = *(const short8*)(xbc + (long)nxt * D_IN);
        }

        float a[8];
#pragma unroll
        for (int j = 0; j < 8; ++j)
            a[j] = (half == 0) ? bf2f((unsigned short)sv[j]) : 0.f;

        int e = bg;
        for (; e + 8 <= en; e += 8) {    // 4 x 1KB wave-loads in flight
            int s0 = esrc[e + half];
            int s1 = esrc[e + 2 + half];
            int s2 = esrc[e + 4 + half];
            int s3 = esrc[e + 6 + half];
            short8 u0 = *(const short8*)(xbc + (long)s0 * D_IN);
            short8 u1 = *(const short8*)(xbc + (long)s1 * D_IN);
            short8 u2 = *(const short8*)(xbc + (long)s2 * D_IN);
            short8 u3 = *(const short8*)(xbc + (long)s3 * D_IN);
#pragma unroll
            for (int j = 0; j < 8; ++j) {
                float t0 = bf2f((unsigned short)u0[j]) + bf2f((unsigned short)u1[j]);
                float t1 = bf2f((unsigned short)u2[j]) + bf2f((unsigned short)u3[j]);
                a[j] += t0 + t1;
            }
        }
        for (; e < en; e += 2) {
            int j0 = e + half;
            int jj = (j0 < en) ? j0 : en - 1;
            int s = esrc[jj];
            float w = (j0 < en) ? 1.f : 0.f;   // mask inactive half
            short8 u = *(const short8*)(xbc + (long)s * D_IN);
#pragma unroll
            for (int j = 0; j < 8; ++j)
                a[j] += w * bf2f((unsigned short)u[j]);
        }

#pragma unroll
        for (int j = 0; j < 8; ++j) a[j] += __shfl_xor(a[j], 32, 64);

        if (half == 0) {
            short8 o;
#pragma unroll
            for (int j = 0; j < 8; ++j) o[j] = (short)f2bf(a[j] * di);
            *(short8*)(aggb + (long)node * D_IN + colofs) = o;
        }

        if (!has) break;
        node = nxt; bg = en; en = en2; di = di2; sv = sv2;
    }
}

// ============ BK=64 swizzled-LDS 128x128 GEMM machinery ============
// LDS tile: 128 rows x 64 shorts (128 B/row); 16B chunk ci of row stored at
// slot ci ^ (row & 7)  -> fragment ds_read_b128 spreads 8 rows over 8 slots.
__device__ __forceinline__ void async_cp16(const unsigned short* gp, unsigned short* lp) {
    __builtin_amdgcn_global_load_lds((const __attribute__((address_space(1))) void*)gp,
                                     (__attribute__((address_space(3))) void*)lp, 16, 0, 0);
}

__device__ __forceinline__ void stage_sw64(const unsigned short* src, int strideK,
                                           int rowMax, unsigned short* lds, int tid) {
#pragma unroll
    for (int rr = 0; rr < 4; ++rr) {
        int c = rr * 256 + tid;          // 0..1023 16B chunks
        int row = c >> 3;
        int ci = (c & 7) ^ (row & 7);    // logical chunk stored at this slot
        if (row > rowMax) row = rowMax;
        async_cp16(src + (long)row * strideK + ci * 8, lds + c * 8);
    }
}

__device__ __forceinline__ bool map_block(int b, int M, int& m0, int& n0) {
    int x = b & 7, slot = b >> 3;
    int mt = x + 8 * (slot >> 2);
    m0 = mt * 128; n0 = (slot & 3) * 128;
    return m0 < M;
}

// ---- GEMM1: C[M,512] = bf16(leaky(A[M,K] @ Bt[512,K]^T + bias)), LDS-staged store ----
__global__ __launch_bounds__(256) void k_gemm_bf16(const unsigned short* __restrict__ A,
                                                   const unsigned short* __restrict__ Bt,
                                                   const float* __restrict__ bias,
                                                   unsigned short* __restrict__ C,
                                                   int M, int K) {
    __shared__ __align__(16) unsigned short As[128 * 64];   // 16 KB
    __shared__ __align__(16) unsigned short Bs[128 * 64];   // 16 KB
    __shared__ __align__(16) unsigned short Ep[32 * 128];   // epilogue staging, 8 KB
    const int tid  = threadIdx.x;
    const int lane = tid & 63, wave = tid >> 6;
    int m0, n0;
    if (!map_block(blockIdx.x, M, m0, n0)) return;
    const int r = lane & 15, q = lane >> 4;
    const int xv = r & 7;                      // XOR swizzle value for this lane's rows
    const int wm = (wave & 1) * 64, wn = (wave >> 1) * 64;
    const int band = wm >> 6;

    floatx4 acc[4][4];
#pragma unroll
    for (int i = 0; i < 4; ++i)
#pragma unroll
        for (int j = 0; j < 4; ++j) acc[i][j] = (floatx4){0.f, 0.f, 0.f, 0.f};

    for (int k0 = 0; k0 < K; k0 += 64) {
        stage_sw64(A + (long)m0 * K + k0, K, M - 1 - m0, As, tid);
        stage_sw64(Bt + (long)n0 * K + k0, K, 127, Bs, tid);
        __syncthreads();

#pragma unroll
        for (int s = 0; s < 2; ++s) {          // two K=32 sub-steps per tile
            int slotbase = s * 4 + q;
            short8 af[4], bf[4];
#pragma unroll
            for (int i = 0; i < 4; ++i)
                af[i] = *(const short8*)(As + (wm + i * 16 + r) * 64 + (slotbase ^ xv) * 8);
#pragma unroll
            for (int j = 0; j < 4; ++j)
                bf[j] = *(const short8*)(Bs + (wn + j * 16 + r) * 64 + (slotbase ^ xv) * 8);
#pragma unroll
            for (int i = 0; i < 4; ++i)
#pragma unroll
                for (int j = 0; j < 4; ++j)
                    acc[i][j] = __builtin_amdgcn_mfma_f32_16x16x32_bf16(af[i], bf[j], acc[i][j], 0, 0, 0);
        }
        __syncthreads();
    }

    // epilogue: per i-band, stage 32 rows x 128 cols bf16 in LDS, then 16B/lane stores
    float bv[4];
#pragma unroll
    for (int j = 0; j < 4; ++j) bv[j] = bias[n0 + wn + j * 16 + r];

#pragma unroll
    for (int i = 0; i < 4; ++i) {
#pragma unroll
        for (int j = 0; j < 4; ++j) {
#pragma unroll
            for (int t2 = 0; t2 < 4; ++t2) {
                float v = acc[i][j][t2] + bv[j];
                v = v > 0.f ? v : NEG_SLOPE * v;
                Ep[(band * 16 + q * 4 + t2) * 128 + wn + j * 16 + r] = f2bf(v);
            }
        }
        __syncthreads();
#pragma unroll
        for (int rr = 0; rr < 2; ++rr) {
            int c = rr * 256 + tid;
            int lrow = c >> 4, ccol = c & 15;
            int grow = m0 + (lrow >> 4) * 64 + i * 16 + (lrow & 15);
            if (grow < M) {
                short8 v = *(const short8*)(Ep + lrow * 128 + ccol * 8);
                *(short8*)(C + (long)grow * D_HID + n0 + ccol * 8) = v;
            }
        }
        __syncthreads();
    }
}

// ---- GEMM2 fused with head: out[row] += sum_col leaky(A@Bt^T + b2) * wout[col] ----
__global__ __launch_bounds__(256) void k_gemm2f(const unsigned short* __restrict__ A,
                                                const unsigned short* __restrict__ Bt,
                                                const float* __restrict__ bias,
                                                const float* __restrict__ wout,
                                                float* __restrict__ out,
                                                int M, int K) {
    __shared__ __align__(16) unsigned short As[128 * 64];
    __shared__ __align__(16) unsigned short Bs[128 * 64];
    const int tid  = threadIdx.x;
    const int lane = tid & 63, wave = tid >> 6;
    int m0, n0;
    if (!map_block(blockIdx.x, M, m0, n0)) return;
    const int r = lane & 15, q = lane >> 4;
    const int xv = r & 7;
    const int wm = (wave & 1) * 64, wn = (wave >> 1) * 64;

    floatx4 acc[4][4];
#pragma unroll
    for (int i = 0; i < 4; ++i)
#pragma unroll
        for (int j = 0; j < 4; ++j) acc[i][j] = (floatx4){0.f, 0.f, 0.f, 0.f};

    for (int k0 = 0; k0 < K; k0 += 64) {
        stage_sw64(A + (long)m0 * K + k0, K, M - 1 - m0, As, tid);
        stage_sw64(Bt + (long)n0 * K + k0, K, 127, Bs, tid);
        __syncthreads();

#pragma unroll
        for (int s = 0; s < 2; ++s) {
            int slotbase = s * 4 + q;
            short8 af[4], bf[4];
#pragma unroll
            for (int i = 0; i < 4; ++i)
                af[i] = *(const short8*)(As + (wm + i * 16 + r) * 64 + (slotbase ^ xv) * 8);
#pragma unroll
            for (int j = 0; j < 4; ++j)
                bf[j] = *(const short8*)(Bs + (wn + j * 16 + r) * 64 + (slotbase ^ xv) * 8);
#pragma unroll
            for (int i = 0; i < 4; ++i)
#pragma unroll
                for (int j = 0; j < 4; ++j)
                    acc[i][j] = __builtin_amdgcn_mfma_f32_16x16x32_bf16(af[i], bf[j], acc[i][j], 0, 0, 0);
        }
        __syncthreads();
    }

    float bv[4], wv[4];
#pragma unroll
    for (int j = 0; j < 4; ++j) {
        int col = n0 + wn + j * 16 + r;
        bv[j] = bias[col];
        wv[j] = wout[col];
    }
#pragma unroll
    for (int i = 0; i < 4; ++i) {
#pragma unroll
        for (int t2 = 0; t2 < 4; ++t2) {
            float p = 0.f;
#pragma unroll
            for (int j = 0; j < 4; ++j) {
                float v = acc[i][j][t2] + bv[j];
                v = v > 0.f ? v : NEG_SLOPE * v;
                p += v * wv[j];
            }
            p += __shfl_xor(p, 8, 64);
            p += __shfl_xor(p, 4, 64);
            p += __shfl_xor(p, 2, 64);
            p += __shfl_xor(p, 1, 64);
            if (r == 0) {
                int row = m0 + wm + i * 16 + q * 4 + t2;
                if (row < M) atomicAdd(&out[row], p);   // out pre-seeded with b_out
            }
        }
    }
}

extern "C" void kernel_launch(void* const* d_in, const int* in_sizes, int n_in,
                              void* d_out, int out_size, void* d_ws, size_t ws_size,
                              hipStream_t stream) {
    const float* x     = (const float*)d_in[0];
    const void*  ei    = d_in[1];
    const float* W_gcn = (const float*)d_in[2];
    const float* b_gcn = (const float*)d_in[3];
    const float* W2    = (const float*)d_in[4];
    const float* b2    = (const float*)d_in[5];
    const float* W_out = (const float*)d_in[6];
    const float* b_out = (const float*)d_in[7];
    float* out = (float*)d_out;

    const int N = in_sizes[0] / D_IN;
    const int E = in_sizes[1] / 2;
    const int NB = (N + SCAN_CHUNK - 1) / SCAN_CHUNK;

    char* w = (char*)d_ws;
    size_t off = 0;
    auto alloc = [&](size_t bytes) { char* p = w + off; off = (off + bytes + 255) & ~(size_t)255; return p; };
    int*            flag   = (int*)alloc(256);
    float*          dinv   = (float*)alloc((size_t)N * 4);
    int*            deg_i  = (int*)alloc((size_t)N * 4);
    int*            offs   = (int*)alloc((size_t)(N + 1) * 4);
    int*            cursor = (int*)alloc((size_t)N * 4);
    int*            bsum   = (int*)alloc((size_t)NB * 4);
    int*            esrc   = (int*)alloc((size_t)(E + 16) * 4);
    unsigned short* xb     = (unsigned short*)alloc((size_t)N * D_IN * 2);
    unsigned short* aggb   = (unsigned short*)alloc((size_t)N * D_IN * 2);
    unsigned short* h1     = (unsigned short*)alloc((size_t)N * D_HID * 2);
    unsigned short* Wgt    = (unsigned short*)alloc((size_t)D_IN * D_HID * 2);
    unsigned short* W2t    = (unsigned short*)alloc((size_t)D_HID * D_HID * 2);

    int npairs = E < 2048 ? E : 2048;
    k_init<<<(N + 255) / 256, 256, 0, stream>>>(deg_i, N, (const unsigned int*)ei,
                                                npairs, flag, b_out, out);
    k_wtrans<<<96, 256, 0, stream>>>(W_gcn, Wgt, W2, W2t);

    k_deg_count<<<(E + 255) / 256, 256, 0, stream>>>(ei, flag, deg_i, E);
    k_scan1<<<NB, 256, 0, stream>>>(deg_i, bsum, N);
    k_scan23<<<NB, 256, 0, stream>>>(deg_i, bsum, NB, offs, cursor, dinv, N);

    long pthreads = (long)N * D_IN / 4;
    k_prescale<<<(unsigned)((pthreads + 255) / 256), 256, 0, stream>>>(x, dinv, xb, N);
    k_fill<<<(E + 255) / 256, 256, 0, stream>>>(ei, flag, cursor, esrc, E);

    int gblocks_gather = GATHER_BLOCKS;
    int nwaves = gblocks_gather * 4;
    k_gather<<<gblocks_gather, 256, 0, stream>>>(xb, offs, esrc, dinv, aggb, N, nwaves);

    int mtiles = (N + 127) / 128;
    int gblocks = ((mtiles + 7) / 8) * 8 * 4;
    k_gemm_bf16<<<gblocks, 256, 0, stream>>>(aggb, Wgt, b_gcn, h1, N, D_IN);
    k_gemm2f<<<gblocks, 256, 0, stream>>>(h1, W2t, b2, W_out, out, N, D_HID);
}

// Round 4
// 336.659 us; speedup vs baseline: 1.0047x; 1.0047x over previous
//
#include <hip/hip_runtime.h>

#define D_IN  256
#define D_HID 512
#define NEG_SLOPE 0.2f
#define SCAN_CHUNK 2048

typedef __attribute__((ext_vector_type(8))) short short8;
typedef __attribute__((ext_vector_type(4))) float floatx4;

__device__ __forceinline__ unsigned short f2bf(float f) {
    unsigned int u = __float_as_uint(f);
    u += 0x7fffu + ((u >> 16) & 1u);   // round-to-nearest-even
    return (unsigned short)(u >> 16);
}
__device__ __forceinline__ float bf2f(unsigned short u) {
    return __uint_as_float(((unsigned int)u) << 16);
}

__device__ __forceinline__ int eidx(const void* ei, long pos, int is64) {
    return is64 ? (int)((const long long*)ei)[pos] : ((const int*)ei)[pos];
}

// ---- merged init: blocks 0..95 do LDS-tiled weight transposes; rest zero deg,
//      seed out=b_out; block 96 additionally detects edge dtype ----
__global__ __launch_bounds__(256) void k_init(int* __restrict__ deg, int N,
                                              const unsigned int* __restrict__ ei,
                                              int npairs, int* flag,
                                              const float* __restrict__ b_out,
                                              float* __restrict__ out,
                                              const float* __restrict__ Wa,
                                              unsigned short* __restrict__ Wat,
                                              const float* __restrict__ Wb,
                                              unsigned short* __restrict__ Wbt) {
    __shared__ float tl[64][65];
    int b = blockIdx.x;
    if (b < 96) {                      // weight transpose, coalesced both ways
        const float* W; unsigned short* Wt; int K, Nc, tk, tn;
        if (b < 32) { W = Wa; Wt = Wat; K = 256; Nc = 512; tk = b & 3; tn = b >> 2; }
        else { b -= 32; W = Wb; Wt = Wbt; K = 512; Nc = 512; tk = b & 7; tn = b >> 3; }
        int k0 = tk * 64, n0 = tn * 64;
        int c = threadIdx.x & 63;
        int r0 = threadIdx.x >> 6;
#pragma unroll
        for (int i = 0; i < 16; ++i) {
            int r = r0 + i * 4;
            tl[r][c] = W[(long)(k0 + r) * Nc + n0 + c];
        }
        __syncthreads();
#pragma unroll
        for (int i = 0; i < 16; ++i) {
            int r = r0 + i * 4;
            Wt[(long)(n0 + r) * K + k0 + c] = f2bf(tl[c][r]);
        }
        return;
    }
    if (b == 96) {                     // dtype detect
        __shared__ int nz;
        if (threadIdx.x == 0) nz = 0;
        __syncthreads();
        for (int p = threadIdx.x; p < npairs; p += blockDim.x)
            if (ei[2 * p + 1] != 0) nz = 1;
        __syncthreads();
        if (threadIdx.x == 0) *flag = nz ? 0 : 1;   // 1 => int64
    }
    int t = (b - 96) * 256 + threadIdx.x;
    if (t < N) { deg[t] = 0; out[t] = b_out[0]; }   // gemm2f atomically adds on top
}

// ---- degree count (int only) ----
__global__ void k_deg_count(const void* __restrict__ ei, const int* __restrict__ flag,
                            int* __restrict__ deg, int E) {
    int e = blockIdx.x * blockDim.x + threadIdx.x;
    if (e < E) atomicAdd(&deg[eidx(ei, (long)E + e, *flag)], 1);
}

// ---- scan phase 1: per-chunk sums ----
__global__ __launch_bounds__(256) void k_scan1(const int* __restrict__ deg,
                                               int* __restrict__ bsum, int N) {
    int base = blockIdx.x * SCAN_CHUNK;
    int hi = min(base + SCAN_CHUNK, N);
    int s = 0;
    for (int i = base + threadIdx.x; i < hi; i += 256) s += deg[i];
#pragma unroll
    for (int off = 32; off > 0; off >>= 1) s += __shfl_down(s, off, 64);
    __shared__ int lds[4];
    if ((threadIdx.x & 63) == 0) lds[threadIdx.x >> 6] = s;
    __syncthreads();
    if (threadIdx.x == 0) bsum[blockIdx.x] = lds[0] + lds[1] + lds[2] + lds[3];
}

// ---- scan phases 2+3 merged ----
__global__ __launch_bounds__(256) void k_scan23(const int* __restrict__ deg,
                                                const int* __restrict__ bsum, int NB,
                                                int* __restrict__ offs,
                                                int* __restrict__ cursor,
                                                float* __restrict__ dinv, int N) {
    __shared__ int lds[256];
    int t = threadIdx.x;
    int bbase = 0;
    for (int i = 0; i < NB; ++i) bbase += (i < blockIdx.x) ? bsum[i] : 0;
    if (blockIdx.x == NB - 1 && t == 0) offs[N] = bbase + bsum[NB - 1];
    int base = blockIdx.x * SCAN_CHUNK;
    int lo = base + t * 8;
    int v[8], s = 0;
#pragma unroll
    for (int j = 0; j < 8; ++j) {
        int i = lo + j;
        v[j] = (i < N) ? deg[i] : 0;
        s += v[j];
    }
    lds[t] = s;
    __syncthreads();
    for (int d = 1; d < 256; d <<= 1) {
        int add = (t >= d) ? lds[t - d] : 0;
        __syncthreads();
        lds[t] += add;
        __syncthreads();
    }
    int run = bbase + ((t > 0) ? lds[t - 1] : 0);
#pragma unroll
    for (int j = 0; j < 8; ++j) {
        int i = lo + j;
        if (i < N) {
            offs[i] = run; cursor[i] = run;
            dinv[i] = rsqrtf(1.0f + (float)v[j]);
            run += v[j];
        }
    }
}

// ---- merged prescale + fill (both depend only on scan23, independent of each other) ----
// blocks [0,PB): xb = bf16(dinv*x). blocks [PB,..): CSR fill.
__global__ __launch_bounds__(256) void k_prefill(const float* __restrict__ x,
                                                 const float* __restrict__ dinv,
                                                 unsigned short* __restrict__ xb,
                                                 const void* __restrict__ ei,
                                                 const int* __restrict__ flag,
                                                 int* __restrict__ cursor,
                                                 int* __restrict__ esrc,
                                                 int N, int E, int PB) {
    if ((int)blockIdx.x < PB) {
        long t = (long)blockIdx.x * 256 + threadIdx.x;   // 1 thread = 4 floats
        long total = (long)N * D_IN / 4;
        if (t >= total) return;
        int row = (int)(t >> 6);
        float s = dinv[row];
        float4 v = *(const float4*)(x + t * 4);
        ushort4 o;
        o.x = f2bf(v.x * s); o.y = f2bf(v.y * s); o.z = f2bf(v.z * s); o.w = f2bf(v.w * s);
        *(ushort4*)(xb + t * 4) = o;
        return;
    }
    int e = (blockIdx.x - PB) * 256 + threadIdx.x;
    if (e >= E) return;
    int is64 = *flag;
    int s = eidx(ei, e, is64), d = eidx(ei, (long)E + e, is64);
    int pos = atomicAdd(&cursor[d], 1);
    esrc[pos] = s;
}

// ---- gather: wave=node (dynamic HW balancing), pre-scaled rows, 8-edge unroll ----
__global__ __launch_bounds__(256) void k_gather(const unsigned short* __restrict__ xb,
                                                const int* __restrict__ offs,
                                                const int* __restrict__ esrc,
                                                const float* __restrict__ dinv,
                                                unsigned short* __restrict__ aggb, int N) {
    int node = blockIdx.x * 4 + (threadIdx.x >> 6);
    if (node >= N) return;
    int lane = threadIdx.x & 63;
    int half = lane >> 5;
    int colofs = (lane & 31) * 8;
    const unsigned short* xbc = xb + colofs;
    float di = dinv[node];

    float a[8];
    {
        short8 v = *(const short8*)(xbc + (long)node * D_IN);   // already dinv[node]*x
#pragma unroll
        for (int j = 0; j < 8; ++j)
            a[j] = (half == 0) ? bf2f((unsigned short)v[j]) : 0.f;
    }

    int beg = offs[node], end = offs[node + 1];
    int e = beg;
    for (; e + 8 <= end; e += 8) {      // 4 x 1KB wave-loads in flight
        int s0 = esrc[e + half];
        int s1 = esrc[e + 2 + half];
        int s2 = esrc[e + 4 + half];
        int s3 = esrc[e + 6 + half];
        short8 u0 = *(const short8*)(xbc + (long)s0 * D_IN);
        short8 u1 = *(const short8*)(xbc + (long)s1 * D_IN);
        short8 u2 = *(const short8*)(xbc + (long)s2 * D_IN);
        short8 u3 = *(const short8*)(xbc + (long)s3 * D_IN);
#pragma unroll
        for (int j = 0; j < 8; ++j) {
            float t0 = bf2f((unsigned short)u0[j]) + bf2f((unsigned short)u1[j]);
            float t1 = bf2f((unsigned short)u2[j]) + bf2f((unsigned short)u3[j]);
            a[j] += t0 + t1;
        }
    }
    for (; e < end; e += 2) {
        int j0 = e + half;
        int jj = (j0 < end) ? j0 : end - 1;
        int s = esrc[jj];
        float w = (j0 < end) ? 1.f : 0.f;   // mask inactive half
        short8 u = *(const short8*)(xbc + (long)s * D_IN);
#pragma unroll
        for (int j = 0; j < 8; ++j)
            a[j] += w * bf2f((unsigned short)u[j]);
    }

#pragma unroll
    for (int j = 0; j < 8; ++j) a[j] += __shfl_xor(a[j], 32, 64);

    if (half == 0) {
        short8 o;
#pragma unroll
        for (int j = 0; j < 8; ++j) o[j] = (short)f2bf(a[j] * di);
        *(short8*)(aggb + (long)node * D_IN + colofs) = o;
    }
}

// ============ BK=64 swizzled-LDS 128x128 GEMM, 2-phase double-buffered ============
// LDS tile: 128 rows x 64 shorts (128 B/row); 16B chunk ci of row stored at
// slot ci ^ (row & 7). K-loop: issue next tile's global_load_lds BEFORE the MFMAs
// on the current tile; the loop-end __syncthreads (vmcnt(0)+barrier) drains it
// after MFMA covered the latency. One barrier per K-step instead of two.
__device__ __forceinline__ void async_cp16(const unsigned short* gp, unsigned short* lp) {
    __builtin_amdgcn_global_load_lds((const __attribute__((address_space(1))) void*)gp,
                                     (__attribute__((address_space(3))) void*)lp, 16, 0, 0);
}

__device__ __forceinline__ void stage_sw64(const unsigned short* src, int strideK,
                                           int rowMax, unsigned short* lds, int tid) {
#pragma unroll
    for (int rr = 0; rr < 4; ++rr) {
        int c = rr * 256 + tid;          // 0..1023 16B chunks
        int row = c >> 3;
        int ci = (c & 7) ^ (row & 7);    // logical chunk stored at this slot
        if (row > rowMax) row = rowMax;
        async_cp16(src + (long)row * strideK + ci * 8, lds + c * 8);
    }
}

__device__ __forceinline__ bool map_block(int b, int M, int& m0, int& n0) {
    int x = b & 7, slot = b >> 3;
    int mt = x + 8 * (slot >> 2);
    m0 = mt * 128; n0 = (slot & 3) * 128;
    return m0 < M;
}

// ---- GEMM1: C[M,512] = bf16(leaky(A[M,K] @ Bt[512,K]^T + bias)), LDS-staged store ----
__global__ __launch_bounds__(256) void k_gemm_bf16(const unsigned short* __restrict__ A,
                                                   const unsigned short* __restrict__ Bt,
                                                   const float* __restrict__ bias,
                                                   unsigned short* __restrict__ C,
                                                   int M, int K) {
    __shared__ __align__(16) unsigned short As[2][128 * 64];   // 32 KB
    __shared__ __align__(16) unsigned short Bs[2][128 * 64];   // 32 KB
    __shared__ __align__(16) unsigned short Ep[32 * 128];      // epilogue staging, 8 KB
    const int tid  = threadIdx.x;
    const int lane = tid & 63, wave = tid >> 6;
    int m0, n0;
    if (!map_block(blockIdx.x, M, m0, n0)) return;
    const int r = lane & 15, q = lane >> 4;
    const int xv = r & 7;
    const int wm = (wave & 1) * 64, wn = (wave >> 1) * 64;
    const int band = wm >> 6;
    const int rmA = M - 1 - m0;
    const unsigned short* Ab = A + (long)m0 * K;
    const unsigned short* Bb = Bt + (long)n0 * K;

    floatx4 acc[4][4];
#pragma unroll
    for (int i = 0; i < 4; ++i)
#pragma unroll
        for (int j = 0; j < 4; ++j) acc[i][j] = (floatx4){0.f, 0.f, 0.f, 0.f};

    const int nt = K >> 6;
    stage_sw64(Ab, K, rmA, As[0], tid);
    stage_sw64(Bb, K, 127, Bs[0], tid);
    __syncthreads();
    for (int t = 0; t < nt; ++t) {
        const int cur = t & 1;
        if (t + 1 < nt) {                       // prefetch next tile (overlaps MFMA)
            stage_sw64(Ab + (t + 1) * 64, K, rmA, As[cur ^ 1], tid);
            stage_sw64(Bb + (t + 1) * 64, K, 127, Bs[cur ^ 1], tid);
        }
#pragma unroll
        for (int s = 0; s < 2; ++s) {           // two K=32 sub-steps per tile
            int slotbase = s * 4 + q;
            short8 af[4], bf[4];
#pragma unroll
            for (int i = 0; i < 4; ++i)
                af[i] = *(const short8*)(As[cur] + (wm + i * 16 + r) * 64 + (slotbase ^ xv) * 8);
#pragma unroll
            for (int j = 0; j < 4; ++j)
                bf[j] = *(const short8*)(Bs[cur] + (wn + j * 16 + r) * 64 + (slotbase ^ xv) * 8);
#pragma unroll
            for (int i = 0; i < 4; ++i)
#pragma unroll
                for (int j = 0; j < 4; ++j)
                    acc[i][j] = __builtin_amdgcn_mfma_f32_16x16x32_bf16(af[i], bf[j], acc[i][j], 0, 0, 0);
        }
        __syncthreads();                        // vmcnt(0) drain + buffer handoff
    }

    // epilogue: per i-band, stage 32 rows x 128 cols bf16 in LDS, then 16B/lane stores
    float bv[4];
#pragma unroll
    for (int j = 0; j < 4; ++j) bv[j] = bias[n0 + wn + j * 16 + r];

#pragma unroll
    for (int i = 0; i < 4; ++i) {
#pragma unroll
        for (int j = 0; j < 4; ++j) {
#pragma unroll
            for (int t2 = 0; t2 < 4; ++t2) {
                float v = acc[i][j][t2] + bv[j];
                v = v > 0.f ? v : NEG_SLOPE * v;
                Ep[(band * 16 + q * 4 + t2) * 128 + wn + j * 16 + r] = f2bf(v);
            }
        }
        __syncthreads();
#pragma unroll
        for (int rr = 0; rr < 2; ++rr) {
            int c = rr * 256 + tid;
            int lrow = c >> 4, ccol = c & 15;
            int grow = m0 + (lrow >> 4) * 64 + i * 16 + (lrow & 15);
            if (grow < M) {
                short8 v = *(const short8*)(Ep + lrow * 128 + ccol * 8);
                *(short8*)(C + (long)grow * D_HID + n0 + ccol * 8) = v;
            }
        }
        __syncthreads();
    }
}

// ---- GEMM2 fused with head: out[row] += sum_col leaky(A@Bt^T + b2) * wout[col] ----
__global__ __launch_bounds__(256) void k_gemm2f(const unsigned short* __restrict__ A,
                                                const unsigned short* __restrict__ Bt,
                                                const float* __restrict__ bias,
                                                const float* __restrict__ wout,
                                                float* __restrict__ out,
                                                int M, int K) {
    __shared__ __align__(16) unsigned short As[2][128 * 64];
    __shared__ __align__(16) unsigned short Bs[2][128 * 64];
    const int tid  = threadIdx.x;
    const int lane = tid & 63, wave = tid >> 6;
    int m0, n0;
    if (!map_block(blockIdx.x, M, m0, n0)) return;
    const int r = lane & 15, q = lane >> 4;
    const int xv = r & 7;
    const int wm = (wave & 1) * 64, wn = (wave >> 1) * 64;
    const int rmA = M - 1 - m0;
    const unsigned short* Ab = A + (long)m0 * K;
    const unsigned short* Bb = Bt + (long)n0 * K;

    floatx4 acc[4][4];
#pragma unroll
    for (int i = 0; i < 4; ++i)
#pragma unroll
        for (int j = 0; j < 4; ++j) acc[i][j] = (floatx4){0.f, 0.f, 0.f, 0.f};

    const int nt = K >> 6;
    stage_sw64(Ab, K, rmA, As[0], tid);
    stage_sw64(Bb, K, 127, Bs[0], tid);
    __syncthreads();
    for (int t = 0; t < nt; ++t) {
        const int cur = t & 1;
        if (t + 1 < nt) {
            stage_sw64(Ab + (t + 1) * 64, K, rmA, As[cur ^ 1], tid);
            stage_sw64(Bb + (t + 1) * 64, K, 127, Bs[cur ^ 1], tid);
        }
#pragma unroll
        for (int s = 0; s < 2; ++s) {
            int slotbase = s * 4 + q;
            short8 af[4], bf[4];
#pragma unroll
            for (int i = 0; i < 4; ++i)
                af[i] = *(const short8*)(As[cur] + (wm + i * 16 + r) * 64 + (slotbase ^ xv) * 8);
#pragma unroll
            for (int j = 0; j < 4; ++j)
                bf[j] = *(const short8*)(Bs[cur] + (wn + j * 16 + r) * 64 + (slotbase ^ xv) * 8);
#pragma unroll
            for (int i = 0; i < 4; ++i)
#pragma unroll
                for (int j = 0; j < 4; ++j)
                    acc[i][j] = __builtin_amdgcn_mfma_f32_16x16x32_bf16(af[i], bf[j], acc[i][j], 0, 0, 0);
        }
        __syncthreads();
    }

    float bv[4], wv[4];
#pragma unroll
    for (int j = 0; j < 4; ++j) {
        int col = n0 + wn + j * 16 + r;
        bv[j] = bias[col];
        wv[j] = wout[col];
    }
#pragma unroll
    for (int i = 0; i < 4; ++i) {
#pragma unroll
        for (int t2 = 0; t2 < 4; ++t2) {
            float p = 0.f;
#pragma unroll
            for (int j = 0; j < 4; ++j) {
                float v = acc[i][j][t2] + bv[j];
                v = v > 0.f ? v : NEG_SLOPE * v;
                p += v * wv[j];
            }
            p += __shfl_xor(p, 8, 64);
            p += __shfl_xor(p, 4, 64);
            p += __shfl_xor(p, 2, 64);
            p += __shfl_xor(p, 1, 64);
            if (r == 0) {
                int row = m0 + wm + i * 16 + q * 4 + t2;
                if (row < M) atomicAdd(&out[row], p);   // out pre-seeded with b_out
            }
        }
    }
}

extern "C" void kernel_launch(void* const* d_in, const int* in_sizes, int n_in,
                              void* d_out, int out_size, void* d_ws, size_t ws_size,
                              hipStream_t stream) {
    const float* x     = (const float*)d_in[0];
    const void*  ei    = d_in[1];
    const float* W_gcn = (const float*)d_in[2];
    const float* b_gcn = (const float*)d_in[3];
    const float* W2    = (const float*)d_in[4];
    const float* b2    = (const float*)d_in[5];
    const float* W_out = (const float*)d_in[6];
    const float* b_out = (const float*)d_in[7];
    float* out = (float*)d_out;

    const int N = in_sizes[0] / D_IN;
    const int E = in_sizes[1] / 2;
    const int NB = (N + SCAN_CHUNK - 1) / SCAN_CHUNK;

    char* w = (char*)d_ws;
    size_t off = 0;
    auto alloc = [&](size_t bytes) { char* p = w + off; off = (off + bytes + 255) & ~(size_t)255; return p; };
    int*            flag   = (int*)alloc(256);
    float*          dinv   = (float*)alloc((size_t)N * 4);
    int*            deg_i  = (int*)alloc((size_t)N * 4);
    int*            offs   = (int*)alloc((size_t)(N + 1) * 4);
    int*            cursor = (int*)alloc((size_t)N * 4);
    int*            bsum   = (int*)alloc((size_t)NB * 4);
    int*            esrc   = (int*)alloc((size_t)(E + 16) * 4);
    unsigned short* xb     = (unsigned short*)alloc((size_t)N * D_IN * 2);
    unsigned short* aggb   = (unsigned short*)alloc((size_t)N * D_IN * 2);
    unsigned short* h1     = (unsigned short*)alloc((size_t)N * D_HID * 2);
    unsigned short* Wgt    = (unsigned short*)alloc((size_t)D_IN * D_HID * 2);
    unsigned short* W2t    = (unsigned short*)alloc((size_t)D_HID * D_HID * 2);

    int npairs = E < 2048 ? E : 2048;
    int init_blocks = 96 + (N + 255) / 256;
    k_init<<<init_blocks, 256, 0, stream>>>(deg_i, N, (const unsigned int*)ei,
                                            npairs, flag, b_out, out,
                                            W_gcn, Wgt, W2, W2t);

    k_deg_count<<<(E + 255) / 256, 256, 0, stream>>>(ei, flag, deg_i, E);
    k_scan1<<<NB, 256, 0, stream>>>(deg_i, bsum, N);
    k_scan23<<<NB, 256, 0, stream>>>(deg_i, bsum, NB, offs, cursor, dinv, N);

    int PB = (int)(((long)N * D_IN / 4 + 255) / 256);
    int FB = (E + 255) / 256;
    k_prefill<<<PB + FB, 256, 0, stream>>>(x, dinv, xb, ei, flag, cursor, esrc, N, E, PB);

    k_gather<<<(N + 3) / 4, 256, 0, stream>>>(xb, offs, esrc, dinv, aggb, N);

    int mtiles = (N + 127) / 128;
    int gblocks = ((mtiles + 7) / 8) * 8 * 4;
    k_gemm_bf16<<<gblocks, 256, 0, stream>>>(aggb, Wgt, b_gcn, h1, N, D_IN);
    k_gemm2f<<<gblocks, 256, 0, stream>>>(h1, W2t, b2, W_out, out, N, D_HID);
}

// Round 5
// 296.440 us; speedup vs baseline: 1.1411x; 1.1357x over previous
//
#include <hip/hip_runtime.h>

#define D_IN  256
#define D_HID 512
#define NEG_SLOPE 0.2f
#define SCAN_CHUNK 2048

typedef __attribute__((ext_vector_type(8))) short short8;
typedef __attribute__((ext_vector_type(4))) float floatx4;

__device__ __forceinline__ unsigned short f2bf(float f) {
    unsigned int u = __float_as_uint(f);
    u += 0x7fffu + ((u >> 16) & 1u);   // round-to-nearest-even
    return (unsigned short)(u >> 16);
}
__device__ __forceinline__ float bf2f(unsigned short u) {
    return __uint_as_float(((unsigned int)u) << 16);
}

__device__ __forceinline__ int eidx(const void* ei, long pos, int is64) {
    return is64 ? (int)((const long long*)ei)[pos] : ((const int*)ei)[pos];
}

// ---- init: blocks 0..95 LDS-tiled weight transposes; blocks 96.. convert x->bf16
//      (unscaled), zero deg, seed out=b_out; block 96 also detects edge dtype ----
__global__ __launch_bounds__(256) void k_init(const float* __restrict__ x,
                                              unsigned short* __restrict__ xb,
                                              int* __restrict__ deg, int N,
                                              const unsigned int* __restrict__ ei,
                                              int npairs, int* flag,
                                              const float* __restrict__ b_out,
                                              float* __restrict__ out,
                                              const float* __restrict__ Wa,
                                              unsigned short* __restrict__ Wat,
                                              const float* __restrict__ Wb,
                                              unsigned short* __restrict__ Wbt,
                                              long xthreads) {
    __shared__ float tl[64][65];
    int b = blockIdx.x;
    if (b < 96) {                      // weight transpose, coalesced both ways
        const float* W; unsigned short* Wt; int K, Nc, tk, tn;
        if (b < 32) { W = Wa; Wt = Wat; K = 256; Nc = 512; tk = b & 3; tn = b >> 2; }
        else { b -= 32; W = Wb; Wt = Wbt; K = 512; Nc = 512; tk = b & 7; tn = b >> 3; }
        int k0 = tk * 64, n0 = tn * 64;
        int c = threadIdx.x & 63;
        int r0 = threadIdx.x >> 6;
#pragma unroll
        for (int i = 0; i < 16; ++i) {
            int r = r0 + i * 4;
            tl[r][c] = W[(long)(k0 + r) * Nc + n0 + c];
        }
        __syncthreads();
#pragma unroll
        for (int i = 0; i < 16; ++i) {
            int r = r0 + i * 4;
            Wt[(long)(n0 + r) * K + k0 + c] = f2bf(tl[c][r]);
        }
        return;
    }
    if (b == 96) {                     // dtype detect
        __shared__ int nz;
        if (threadIdx.x == 0) nz = 0;
        __syncthreads();
        for (int p = threadIdx.x; p < npairs; p += blockDim.x)
            if (ei[2 * p + 1] != 0) nz = 1;
        __syncthreads();
        if (threadIdx.x == 0) *flag = nz ? 0 : 1;   // 1 => int64
    }
    long t = (long)(b - 96) * 256 + threadIdx.x;
    if (t < xthreads) {                // 1 thread = 4 floats
        long i = t * 4;
        float4 v = *(const float4*)(x + i);
        ushort4 o;
        o.x = f2bf(v.x); o.y = f2bf(v.y); o.z = f2bf(v.z); o.w = f2bf(v.w);
        *(ushort4*)(xb + i) = o;
    }
    if (t < N) { deg[t] = 0; out[t] = b_out[0]; }   // gemm2f atomically adds on top
}

// ---- degree count + rank capture: ONE atomic pass builds both degree and
//      each edge's slot-within-destination (rank) -> fill needs no atomics ----
__global__ void k_deg_count(const void* __restrict__ ei, const int* __restrict__ flag,
                            int* __restrict__ deg, int* __restrict__ rank, int E) {
    int e = blockIdx.x * blockDim.x + threadIdx.x;
    if (e < E) rank[e] = atomicAdd(&deg[eidx(ei, (long)E + e, *flag)], 1);
}

// ---- scan phase 1: per-chunk sums ----
__global__ __launch_bounds__(256) void k_scan1(const int* __restrict__ deg,
                                               int* __restrict__ bsum, int N) {
    int base = blockIdx.x * SCAN_CHUNK;
    int hi = min(base + SCAN_CHUNK, N);
    int s = 0;
    for (int i = base + threadIdx.x; i < hi; i += 256) s += deg[i];
#pragma unroll
    for (int off = 32; off > 0; off >>= 1) s += __shfl_down(s, off, 64);
    __shared__ int lds[4];
    if ((threadIdx.x & 63) == 0) lds[threadIdx.x >> 6] = s;
    __syncthreads();
    if (threadIdx.x == 0) bsum[blockIdx.x] = lds[0] + lds[1] + lds[2] + lds[3];
}

// ---- scan phases 2+3 merged ----
__global__ __launch_bounds__(256) void k_scan23(const int* __restrict__ deg,
                                                const int* __restrict__ bsum, int NB,
                                                int* __restrict__ offs,
                                                float* __restrict__ dinv, int N) {
    __shared__ int lds[256];
    int t = threadIdx.x;
    int bbase = 0;
    for (int i = 0; i < NB; ++i) bbase += (i < blockIdx.x) ? bsum[i] : 0;
    if (blockIdx.x == NB - 1 && t == 0) offs[N] = bbase + bsum[NB - 1];
    int base = blockIdx.x * SCAN_CHUNK;
    int lo = base + t * 8;
    int v[8], s = 0;
#pragma unroll
    for (int j = 0; j < 8; ++j) {
        int i = lo + j;
        v[j] = (i < N) ? deg[i] : 0;
        s += v[j];
    }
    lds[t] = s;
    __syncthreads();
    for (int d = 1; d < 256; d <<= 1) {
        int add = (t >= d) ? lds[t - d] : 0;
        __syncthreads();
        lds[t] += add;
        __syncthreads();
    }
    int run = bbase + ((t > 0) ? lds[t - 1] : 0);
#pragma unroll
    for (int j = 0; j < 8; ++j) {
        int i = lo + j;
        if (i < N) {
            offs[i] = run;
            dinv[i] = rsqrtf(1.0f + (float)v[j]);
            run += v[j];
        }
    }
}

// ---- fill CSR edge list: atomic-free (offs random READ instead of atomic RMW) ----
__global__ void k_fill(const void* __restrict__ ei, const int* __restrict__ flag,
                       const int* __restrict__ offs, const int* __restrict__ rank,
                       int* __restrict__ esrc, int E) {
    int e = blockIdx.x * blockDim.x + threadIdx.x;
    if (e >= E) return;
    int is64 = *flag;
    int s = eidx(ei, e, is64), d = eidx(ei, (long)E + e, is64);
    esrc[offs[d] + rank[e]] = s;
}

// ---- gather: wave=node, ushort8 loads (16 B/lane), 2 edges/load, 8-edge unroll ----
// (round-0 structure: best measured 58.7 us; dinv[src] loads hide under row loads)
__global__ __launch_bounds__(256) void k_gather(const unsigned short* __restrict__ xb,
                                                const int* __restrict__ offs,
                                                const int* __restrict__ esrc,
                                                const float* __restrict__ dinv,
                                                unsigned short* __restrict__ aggb, int N) {
    int node = blockIdx.x * 4 + (threadIdx.x >> 6);
    int lane = threadIdx.x & 63;
    if (node >= N) return;
    int half = lane >> 5;
    int li   = lane & 31;
    int colofs = li * 8;
    float di = dinv[node];

    float a[8];
    {
        short8 v = *(const short8*)(xb + (long)node * D_IN + colofs);
#pragma unroll
        for (int j = 0; j < 8; ++j)
            a[j] = (half == 0) ? di * bf2f((unsigned short)v[j]) : 0.f;
    }

    int beg = offs[node], end = offs[node + 1];
    int e = beg;
    for (; e + 8 <= end; e += 8) {      // 4 x 1KB wave-loads in flight
        int s0 = esrc[e + half];
        int s1 = esrc[e + 2 + half];
        int s2 = esrc[e + 4 + half];
        int s3 = esrc[e + 6 + half];
        float w0 = dinv[s0], w1 = dinv[s1], w2 = dinv[s2], w3 = dinv[s3];
        short8 u0 = *(const short8*)(xb + (long)s0 * D_IN + colofs);
        short8 u1 = *(const short8*)(xb + (long)s1 * D_IN + colofs);
        short8 u2 = *(const short8*)(xb + (long)s2 * D_IN + colofs);
        short8 u3 = *(const short8*)(xb + (long)s3 * D_IN + colofs);
#pragma unroll
        for (int j = 0; j < 8; ++j)
            a[j] += w0 * bf2f((unsigned short)u0[j]) + w1 * bf2f((unsigned short)u1[j])
                  + w2 * bf2f((unsigned short)u2[j]) + w3 * bf2f((unsigned short)u3[j]);
    }
    for (; e < end; e += 2) {
        int j0 = e + half;
        int jj = (j0 < end) ? j0 : end - 1;
        int s = esrc[jj];
        float w = (j0 < end) ? dinv[s] : 0.f;
        short8 u = *(const short8*)(xb + (long)s * D_IN + colofs);
#pragma unroll
        for (int j = 0; j < 8; ++j)
            a[j] += w * bf2f((unsigned short)u[j]);
    }

#pragma unroll
    for (int j = 0; j < 8; ++j) a[j] += __shfl_xor(a[j], 32, 64);

    if (half == 0) {
        short8 o;
#pragma unroll
        for (int j = 0; j < 8; ++j) o[j] = (short)f2bf(a[j] * di);
        *(short8*)(aggb + (long)node * D_IN + colofs) = o;
    }
}

// ============ BK=64 swizzled-LDS 128x128 GEMM, 2-phase double-buffered ============
// LDS tile: 128 rows x 64 shorts (128 B/row); 16B chunk ci of row stored at
// slot ci ^ (row & 7). K-loop: issue next tile's global_load_lds BEFORE the MFMAs
// on the current tile; the loop-end __syncthreads (vmcnt(0)+barrier) drains it
// after MFMA covered the latency. One barrier per K-step instead of two.
__device__ __forceinline__ void async_cp16(const unsigned short* gp, unsigned short* lp) {
    __builtin_amdgcn_global_load_lds((const __attribute__((address_space(1))) void*)gp,
                                     (__attribute__((address_space(3))) void*)lp, 16, 0, 0);
}

__device__ __forceinline__ void stage_sw64(const unsigned short* src, int strideK,
                                           int rowMax, unsigned short* lds, int tid) {
#pragma unroll
    for (int rr = 0; rr < 4; ++rr) {
        int c = rr * 256 + tid;          // 0..1023 16B chunks
        int row = c >> 3;
        int ci = (c & 7) ^ (row & 7);    // logical chunk stored at this slot
        if (row > rowMax) row = rowMax;
        async_cp16(src + (long)row * strideK + ci * 8, lds + c * 8);
    }
}

__device__ __forceinline__ bool map_block(int b, int M, int& m0, int& n0) {
    int x = b & 7, slot = b >> 3;
    int mt = x + 8 * (slot >> 2);
    m0 = mt * 128; n0 = (slot & 3) * 128;
    return m0 < M;
}

// ---- GEMM1: C[M,512] = bf16(leaky(A[M,K] @ Bt[512,K]^T + bias)), LDS-staged store ----
__global__ __launch_bounds__(256) void k_gemm_bf16(const unsigned short* __restrict__ A,
                                                   const unsigned short* __restrict__ Bt,
                                                   const float* __restrict__ bias,
                                                   unsigned short* __restrict__ C,
                                                   int M, int K) {
    __shared__ __align__(16) unsigned short As[2][128 * 64];   // 32 KB
    __shared__ __align__(16) unsigned short Bs[2][128 * 64];   // 32 KB
    __shared__ __align__(16) unsigned short Ep[32 * 128];      // epilogue staging, 8 KB
    const int tid  = threadIdx.x;
    const int lane = tid & 63, wave = tid >> 6;
    int m0, n0;
    if (!map_block(blockIdx.x, M, m0, n0)) return;
    const int r = lane & 15, q = lane >> 4;
    const int xv = r & 7;
    const int wm = (wave & 1) * 64, wn = (wave >> 1) * 64;
    const int band = wm >> 6;
    const int rmA = M - 1 - m0;
    const unsigned short* Ab = A + (long)m0 * K;
    const unsigned short* Bb = Bt + (long)n0 * K;

    floatx4 acc[4][4];
#pragma unroll
    for (int i = 0; i < 4; ++i)
#pragma unroll
        for (int j = 0; j < 4; ++j) acc[i][j] = (floatx4){0.f, 0.f, 0.f, 0.f};

    const int nt = K >> 6;
    stage_sw64(Ab, K, rmA, As[0], tid);
    stage_sw64(Bb, K, 127, Bs[0], tid);
    __syncthreads();
    for (int t = 0; t < nt; ++t) {
        const int cur = t & 1;
        if (t + 1 < nt) {                       // prefetch next tile (overlaps MFMA)
            stage_sw64(Ab + (t + 1) * 64, K, rmA, As[cur ^ 1], tid);
            stage_sw64(Bb + (t + 1) * 64, K, 127, Bs[cur ^ 1], tid);
        }
#pragma unroll
        for (int s = 0; s < 2; ++s) {           // two K=32 sub-steps per tile
            int slotbase = s * 4 + q;
            short8 af[4], bf[4];
#pragma unroll
            for (int i = 0; i < 4; ++i)
                af[i] = *(const short8*)(As[cur] + (wm + i * 16 + r) * 64 + (slotbase ^ xv) * 8);
#pragma unroll
            for (int j = 0; j < 4; ++j)
                bf[j] = *(const short8*)(Bs[cur] + (wn + j * 16 + r) * 64 + (slotbase ^ xv) * 8);
#pragma unroll
            for (int i = 0; i < 4; ++i)
#pragma unroll
                for (int j = 0; j < 4; ++j)
                    acc[i][j] = __builtin_amdgcn_mfma_f32_16x16x32_bf16(af[i], bf[j], acc[i][j], 0, 0, 0);
        }
        __syncthreads();                        // vmcnt(0) drain + buffer handoff
    }

    // epilogue: per i-band, stage 32 rows x 128 cols bf16 in LDS, then 16B/lane stores
    float bv[4];
#pragma unroll
    for (int j = 0; j < 4; ++j) bv[j] = bias[n0 + wn + j * 16 + r];

#pragma unroll
    for (int i = 0; i < 4; ++i) {
#pragma unroll
        for (int j = 0; j < 4; ++j) {
#pragma unroll
            for (int t2 = 0; t2 < 4; ++t2) {
                float v = acc[i][j][t2] + bv[j];
                v = v > 0.f ? v : NEG_SLOPE * v;
                Ep[(band * 16 + q * 4 + t2) * 128 + wn + j * 16 + r] = f2bf(v);
            }
        }
        __syncthreads();
#pragma unroll
        for (int rr = 0; rr < 2; ++rr) {
            int c = rr * 256 + tid;
            int lrow = c >> 4, ccol = c & 15;
            int grow = m0 + (lrow >> 4) * 64 + i * 16 + (lrow & 15);
            if (grow < M) {
                short8 v = *(const short8*)(Ep + lrow * 128 + ccol * 8);
                *(short8*)(C + (long)grow * D_HID + n0 + ccol * 8) = v;
            }
        }
        __syncthreads();
    }
}

// ---- GEMM2 fused with head: out[row] += sum_col leaky(A@Bt^T + b2) * wout[col] ----
__global__ __launch_bounds__(256) void k_gemm2f(const unsigned short* __restrict__ A,
                                                const unsigned short* __restrict__ Bt,
                                                const float* __restrict__ bias,
                                                const float* __restrict__ wout,
                                                float* __restrict__ out,
                                                int M, int K) {
    __shared__ __align__(16) unsigned short As[2][128 * 64];
    __shared__ __align__(16) unsigned short Bs[2][128 * 64];
    const int tid  = threadIdx.x;
    const int lane = tid & 63, wave = tid >> 6;
    int m0, n0;
    if (!map_block(blockIdx.x, M, m0, n0)) return;
    const int r = lane & 15, q = lane >> 4;
    const int xv = r & 7;
    const int wm = (wave & 1) * 64, wn = (wave >> 1) * 64;
    const int rmA = M - 1 - m0;
    const unsigned short* Ab = A + (long)m0 * K;
    const unsigned short* Bb = Bt + (long)n0 * K;

    floatx4 acc[4][4];
#pragma unroll
    for (int i = 0; i < 4; ++i)
#pragma unroll
        for (int j = 0; j < 4; ++j) acc[i][j] = (floatx4){0.f, 0.f, 0.f, 0.f};

    const int nt = K >> 6;
    stage_sw64(Ab, K, rmA, As[0], tid);
    stage_sw64(Bb, K, 127, Bs[0], tid);
    __syncthreads();
    for (int t = 0; t < nt; ++t) {
        const int cur = t & 1;
        if (t + 1 < nt) {
            stage_sw64(Ab + (t + 1) * 64, K, rmA, As[cur ^ 1], tid);
            stage_sw64(Bb + (t + 1) * 64, K, 127, Bs[cur ^ 1], tid);
        }
#pragma unroll
        for (int s = 0; s < 2; ++s) {
            int slotbase = s * 4 + q;
            short8 af[4], bf[4];
#pragma unroll
            for (int i = 0; i < 4; ++i)
                af[i] = *(const short8*)(As[cur] + (wm + i * 16 + r) * 64 + (slotbase ^ xv) * 8);
#pragma unroll
            for (int j = 0; j < 4; ++j)
                bf[j] = *(const short8*)(Bs[cur] + (wn + j * 16 + r) * 64 + (slotbase ^ xv) * 8);
#pragma unroll
            for (int i = 0; i < 4; ++i)
#pragma unroll
                for (int j = 0; j < 4; ++j)
                    acc[i][j] = __builtin_amdgcn_mfma_f32_16x16x32_bf16(af[i], bf[j], acc[i][j], 0, 0, 0);
        }
        __syncthreads();
    }

    float bv[4], wv[4];
#pragma unroll
    for (int j = 0; j < 4; ++j) {
        int col = n0 + wn + j * 16 + r;
        bv[j] = bias[col];
        wv[j] = wout[col];
    }
#pragma unroll
    for (int i = 0; i < 4; ++i) {
#pragma unroll
        for (int t2 = 0; t2 < 4; ++t2) {
            float p = 0.f;
#pragma unroll
            for (int j = 0; j < 4; ++j) {
                float v = acc[i][j][t2] + bv[j];
                v = v > 0.f ? v : NEG_SLOPE * v;
                p += v * wv[j];
            }
            p += __shfl_xor(p, 8, 64);
            p += __shfl_xor(p, 4, 64);
            p += __shfl_xor(p, 2, 64);
            p += __shfl_xor(p, 1, 64);
            if (r == 0) {
                int row = m0 + wm + i * 16 + q * 4 + t2;
                if (row < M) atomicAdd(&out[row], p);   // out pre-seeded with b_out
            }
        }
    }
}

extern "C" void kernel_launch(void* const* d_in, const int* in_sizes, int n_in,
                              void* d_out, int out_size, void* d_ws, size_t ws_size,
                              hipStream_t stream) {
    const float* x     = (const float*)d_in[0];
    const void*  ei    = d_in[1];
    const float* W_gcn = (const float*)d_in[2];
    const float* b_gcn = (const float*)d_in[3];
    const float* W2    = (const float*)d_in[4];
    const float* b2    = (const float*)d_in[5];
    const float* W_out = (const float*)d_in[6];
    const float* b_out = (const float*)d_in[7];
    float* out = (float*)d_out;

    const int N = in_sizes[0] / D_IN;
    const int E = in_sizes[1] / 2;
    const int NB = (N + SCAN_CHUNK - 1) / SCAN_CHUNK;

    char* w = (char*)d_ws;
    size_t off = 0;
    auto alloc = [&](size_t bytes) { char* p = w + off; off = (off + bytes + 255) & ~(size_t)255; return p; };
    int*            flag   = (int*)alloc(256);
    float*          dinv   = (float*)alloc((size_t)N * 4);
    int*            deg_i  = (int*)alloc((size_t)N * 4);
    int*            offs   = (int*)alloc((size_t)(N + 1) * 4);
    int*            bsum   = (int*)alloc((size_t)NB * 4);
    int*            rank   = (int*)alloc((size_t)(E + 16) * 4);
    int*            esrc   = (int*)alloc((size_t)(E + 16) * 4);
    unsigned short* xb     = (unsigned short*)alloc((size_t)N * D_IN * 2);
    unsigned short* aggb   = (unsigned short*)alloc((size_t)N * D_IN * 2);
    unsigned short* h1     = (unsigned short*)alloc((size_t)N * D_HID * 2);
    unsigned short* Wgt    = (unsigned short*)alloc((size_t)D_IN * D_HID * 2);
    unsigned short* W2t    = (unsigned short*)alloc((size_t)D_HID * D_HID * 2);

    int npairs = E < 2048 ? E : 2048;
    long xthreads = (long)N * D_IN / 4;
    int init_blocks = 96 + (int)((xthreads + 255) / 256);
    k_init<<<init_blocks, 256, 0, stream>>>(x, xb, deg_i, N, (const unsigned int*)ei,
                                            npairs, flag, b_out, out,
                                            W_gcn, Wgt, W2, W2t, xthreads);

    k_deg_count<<<(E + 255) / 256, 256, 0, stream>>>(ei, flag, deg_i, rank, E);
    k_scan1<<<NB, 256, 0, stream>>>(deg_i, bsum, N);
    k_scan23<<<NB, 256, 0, stream>>>(deg_i, bsum, NB, offs, dinv, N);
    k_fill<<<(E + 255) / 256, 256, 0, stream>>>(ei, flag, offs, rank, esrc, E);

    k_gather<<<(N + 3) / 4, 256, 0, stream>>>(xb, offs, esrc, dinv, aggb, N);

    int mtiles = (N + 127) / 128;
    int gblocks = ((mtiles + 7) / 8) * 8 * 4;
    k_gemm_bf16<<<gblocks, 256, 0, stream>>>(aggb, Wgt, b_gcn, h1, N, D_IN);
    k_gemm2f<<<gblocks, 256, 0, stream>>>(h1, W2t, b2, W_out, out, N, D_HID);
}

// Round 6
// 291.542 us; speedup vs baseline: 1.1602x; 1.0168x over previous
//
#include <hip/hip_runtime.h>

#define D_IN  256
#define D_HID 512
#define NEG_SLOPE 0.2f
#define SCAN_CHUNK 2048

typedef __attribute__((ext_vector_type(8))) short short8;
typedef __attribute__((ext_vector_type(4))) float floatx4;

__device__ __forceinline__ unsigned short f2bf(float f) {
    unsigned int u = __float_as_uint(f);
    u += 0x7fffu + ((u >> 16) & 1u);   // round-to-nearest-even
    return (unsigned short)(u >> 16);
}
__device__ __forceinline__ float bf2f(unsigned short u) {
    return __uint_as_float(((unsigned int)u) << 16);
}

__device__ __forceinline__ int eidx(const void* ei, long pos, int is64) {
    return is64 ? (int)((const long long*)ei)[pos] : ((const int*)ei)[pos];
}

// ---- init: blocks 0..95 LDS-tiled weight transposes; blocks 96.. convert x->bf16
//      (unscaled), zero deg, seed out=b_out; block 96 also detects edge dtype ----
__global__ __launch_bounds__(256) void k_init(const float* __restrict__ x,
                                              unsigned short* __restrict__ xb,
                                              int* __restrict__ deg, int N,
                                              const unsigned int* __restrict__ ei,
                                              int npairs, int* flag,
                                              const float* __restrict__ b_out,
                                              float* __restrict__ out,
                                              const float* __restrict__ Wa,
                                              unsigned short* __restrict__ Wat,
                                              const float* __restrict__ Wb,
                                              unsigned short* __restrict__ Wbt,
                                              long xthreads) {
    __shared__ float tl[64][65];
    int b = blockIdx.x;
    if (b < 96) {                      // weight transpose, coalesced both ways
        const float* W; unsigned short* Wt; int K, Nc, tk, tn;
        if (b < 32) { W = Wa; Wt = Wat; K = 256; Nc = 512; tk = b & 3; tn = b >> 2; }
        else { b -= 32; W = Wb; Wt = Wbt; K = 512; Nc = 512; tk = b & 7; tn = b >> 3; }
        int k0 = tk * 64, n0 = tn * 64;
        int c = threadIdx.x & 63;
        int r0 = threadIdx.x >> 6;
#pragma unroll
        for (int i = 0; i < 16; ++i) {
            int r = r0 + i * 4;
            tl[r][c] = W[(long)(k0 + r) * Nc + n0 + c];
        }
        __syncthreads();
#pragma unroll
        for (int i = 0; i < 16; ++i) {
            int r = r0 + i * 4;
            Wt[(long)(n0 + r) * K + k0 + c] = f2bf(tl[c][r]);
        }
        return;
    }
    if (b == 96) {                     // dtype detect
        __shared__ int nz;
        if (threadIdx.x == 0) nz = 0;
        __syncthreads();
        for (int p = threadIdx.x; p < npairs; p += blockDim.x)
            if (ei[2 * p + 1] != 0) nz = 1;
        __syncthreads();
        if (threadIdx.x == 0) *flag = nz ? 0 : 1;   // 1 => int64
    }
    long t = (long)(b - 96) * 256 + threadIdx.x;
    if (t < xthreads) {                // 1 thread = 4 floats
        long i = t * 4;
        float4 v = *(const float4*)(x + i);
        ushort4 o;
        o.x = f2bf(v.x); o.y = f2bf(v.y); o.z = f2bf(v.z); o.w = f2bf(v.w);
        *(ushort4*)(xb + i) = o;
    }
    if (t < N) { deg[t] = 0; out[t] = b_out[0]; }   // gemm2f atomically adds on top
}

// ---- degree count + rank capture: ONE atomic pass builds both degree and
//      each edge's slot-within-destination (rank) -> fill needs no atomics ----
__global__ void k_deg_count(const void* __restrict__ ei, const int* __restrict__ flag,
                            int* __restrict__ deg, int* __restrict__ rank, int E) {
    int e = blockIdx.x * blockDim.x + threadIdx.x;
    if (e < E) rank[e] = atomicAdd(&deg[eidx(ei, (long)E + e, *flag)], 1);
}

// ---- scan phase 1: per-chunk sums ----
__global__ __launch_bounds__(256) void k_scan1(const int* __restrict__ deg,
                                               int* __restrict__ bsum, int N) {
    int base = blockIdx.x * SCAN_CHUNK;
    int hi = min(base + SCAN_CHUNK, N);
    int s = 0;
    for (int i = base + threadIdx.x; i < hi; i += 256) s += deg[i];
#pragma unroll
    for (int off = 32; off > 0; off >>= 1) s += __shfl_down(s, off, 64);
    __shared__ int lds[4];
    if ((threadIdx.x & 63) == 0) lds[threadIdx.x >> 6] = s;
    __syncthreads();
    if (threadIdx.x == 0) bsum[blockIdx.x] = lds[0] + lds[1] + lds[2] + lds[3];
}

// ---- scan phases 2+3 merged ----
__global__ __launch_bounds__(256) void k_scan23(const int* __restrict__ deg,
                                                const int* __restrict__ bsum, int NB,
                                                int* __restrict__ offs,
                                                float* __restrict__ dinv, int N) {
    __shared__ int lds[256];
    int t = threadIdx.x;
    int bbase = 0;
    for (int i = 0; i < NB; ++i) bbase += (i < blockIdx.x) ? bsum[i] : 0;
    if (blockIdx.x == NB - 1 && t == 0) offs[N] = bbase + bsum[NB - 1];
    int base = blockIdx.x * SCAN_CHUNK;
    int lo = base + t * 8;
    int v[8], s = 0;
#pragma unroll
    for (int j = 0; j < 8; ++j) {
        int i = lo + j;
        v[j] = (i < N) ? deg[i] : 0;
        s += v[j];
    }
    lds[t] = s;
    __syncthreads();
    for (int d = 1; d < 256; d <<= 1) {
        int add = (t >= d) ? lds[t - d] : 0;
        __syncthreads();
        lds[t] += add;
        __syncthreads();
    }
    int run = bbase + ((t > 0) ? lds[t - 1] : 0);
#pragma unroll
    for (int j = 0; j < 8; ++j) {
        int i = lo + j;
        if (i < N) {
            offs[i] = run;
            dinv[i] = rsqrtf(1.0f + (float)v[j]);
            run += v[j];
        }
    }
}

// ---- fill CSR edge list: atomic-free (offs random READ instead of atomic RMW) ----
__global__ void k_fill(const void* __restrict__ ei, const int* __restrict__ flag,
                       const int* __restrict__ offs, const int* __restrict__ rank,
                       int* __restrict__ esrc, int E) {
    int e = blockIdx.x * blockDim.x + threadIdx.x;
    if (e >= E) return;
    int is64 = *flag;
    int s = eidx(ei, e, is64), d = eidx(ei, (long)E + e, is64);
    esrc[offs[d] + rank[e]] = s;
}

// ---- gather: wave=node, ushort8 loads (16 B/lane), 2 edges/load, 8-edge unroll ----
// (round-0 structure: best measured 58.7 us; dinv[src] loads hide under row loads)
__global__ __launch_bounds__(256) void k_gather(const unsigned short* __restrict__ xb,
                                                const int* __restrict__ offs,
                                                const int* __restrict__ esrc,
                                                const float* __restrict__ dinv,
                                                unsigned short* __restrict__ aggb, int N) {
    int node = blockIdx.x * 4 + (threadIdx.x >> 6);
    int lane = threadIdx.x & 63;
    if (node >= N) return;
    int half = lane >> 5;
    int li   = lane & 31;
    int colofs = li * 8;
    float di = dinv[node];

    float a[8];
    {
        short8 v = *(const short8*)(xb + (long)node * D_IN + colofs);
#pragma unroll
        for (int j = 0; j < 8; ++j)
            a[j] = (half == 0) ? di * bf2f((unsigned short)v[j]) : 0.f;
    }

    int beg = offs[node], end = offs[node + 1];
    int e = beg;
    for (; e + 8 <= end; e += 8) {      // 4 x 1KB wave-loads in flight
        int s0 = esrc[e + half];
        int s1 = esrc[e + 2 + half];
        int s2 = esrc[e + 4 + half];
        int s3 = esrc[e + 6 + half];
        float w0 = dinv[s0], w1 = dinv[s1], w2 = dinv[s2], w3 = dinv[s3];
        short8 u0 = *(const short8*)(xb + (long)s0 * D_IN + colofs);
        short8 u1 = *(const short8*)(xb + (long)s1 * D_IN + colofs);
        short8 u2 = *(const short8*)(xb + (long)s2 * D_IN + colofs);
        short8 u3 = *(const short8*)(xb + (long)s3 * D_IN + colofs);
#pragma unroll
        for (int j = 0; j < 8; ++j)
            a[j] += w0 * bf2f((unsigned short)u0[j]) + w1 * bf2f((unsigned short)u1[j])
                  + w2 * bf2f((unsigned short)u2[j]) + w3 * bf2f((unsigned short)u3[j]);
    }
    for (; e < end; e += 2) {
        int j0 = e + half;
        int jj = (j0 < end) ? j0 : end - 1;
        int s = esrc[jj];
        float w = (j0 < end) ? dinv[s] : 0.f;
        short8 u = *(const short8*)(xb + (long)s * D_IN + colofs);
#pragma unroll
        for (int j = 0; j < 8; ++j)
            a[j] += w * bf2f((unsigned short)u[j]);
    }

#pragma unroll
    for (int j = 0; j < 8; ++j) a[j] += __shfl_xor(a[j], 32, 64);

    if (half == 0) {
        short8 o;
#pragma unroll
        for (int j = 0; j < 8; ++j) o[j] = (short)f2bf(a[j] * di);
        *(short8*)(aggb + (long)node * D_IN + colofs) = o;
    }
}

// ============ BK=64 swizzled-LDS 128x128 GEMM, counted-vmcnt 2-deep pipeline ======
// LDS tile: 128 rows x 64 shorts (128 B/row); 16B chunk ci of row stored at
// slot ci ^ (row & 7). Pipeline (T4): prologue stages tiles 0 and 1; per K-step
// wait only vmcnt(8) (own younger tile stays in flight), raw s_barrier, compute,
// raw s_barrier, then stage tile t+2 into the buffer just freed. Each stage gets
// a FULL K-step of MFMA to land instead of being drained by __syncthreads.
__device__ __forceinline__ void async_cp16(const unsigned short* gp, unsigned short* lp) {
    __builtin_amdgcn_global_load_lds((const __attribute__((address_space(1))) void*)gp,
                                     (__attribute__((address_space(3))) void*)lp, 16, 0, 0);
}

__device__ __forceinline__ void stage_sw64(const unsigned short* src, int strideK,
                                           int rowMax, unsigned short* lds, int tid) {
#pragma unroll
    for (int rr = 0; rr < 4; ++rr) {
        int c = rr * 256 + tid;          // 0..1023 16B chunks
        int row = c >> 3;
        int ci = (c & 7) ^ (row & 7);    // logical chunk stored at this slot
        if (row > rowMax) row = rowMax;
        async_cp16(src + (long)row * strideK + ci * 8, lds + c * 8);
    }
}

__device__ __forceinline__ bool map_block(int b, int M, int& m0, int& n0) {
    int x = b & 7, slot = b >> 3;
    int mt = x + 8 * (slot >> 2);
    m0 = mt * 128; n0 = (slot & 3) * 128;
    return m0 < M;
}

__device__ __forceinline__ void mfma_step(const unsigned short* As_,
                                          const unsigned short* Bs_,
                                          floatx4 acc[4][4],
                                          int wm, int wn, int r, int q, int xv) {
#pragma unroll
    for (int s = 0; s < 2; ++s) {        // two K=32 sub-steps per tile
        int slotbase = s * 4 + q;
        short8 af[4], bf[4];
#pragma unroll
        for (int i = 0; i < 4; ++i)
            af[i] = *(const short8*)(As_ + (wm + i * 16 + r) * 64 + (slotbase ^ xv) * 8);
#pragma unroll
        for (int j = 0; j < 4; ++j)
            bf[j] = *(const short8*)(Bs_ + (wn + j * 16 + r) * 64 + (slotbase ^ xv) * 8);
#pragma unroll
        for (int i = 0; i < 4; ++i)
#pragma unroll
            for (int j = 0; j < 4; ++j)
                acc[i][j] = __builtin_amdgcn_mfma_f32_16x16x32_bf16(af[i], bf[j], acc[i][j], 0, 0, 0);
    }
}

// K-loop body shared by both GEMMs. 8 global_load_lds per thread per tile:
// vmcnt(8) == "my older tile has fully landed".
#define GEMM_KLOOP(Ab, Bb, K, rmA)                                              \
    const int nt = (K) >> 6;                                                    \
    stage_sw64((Ab), (K), (rmA), As[0], tid);                                   \
    stage_sw64((Bb), (K), 127, Bs[0], tid);                                     \
    if (nt > 1) {                                                               \
        stage_sw64((Ab) + 64, (K), (rmA), As[1], tid);                          \
        stage_sw64((Bb) + 64, (K), 127, Bs[1], tid);                            \
    }                                                                           \
    for (int t = 0; t < nt; ++t) {                                              \
        const int cur = t & 1;                                                  \
        if (t + 1 < nt) asm volatile("s_waitcnt vmcnt(8)" ::: "memory");        \
        else            asm volatile("s_waitcnt vmcnt(0)" ::: "memory");        \
        __builtin_amdgcn_sched_barrier(0);                                      \
        __builtin_amdgcn_s_barrier();                                           \
        __builtin_amdgcn_sched_barrier(0);                                      \
        mfma_step(As[cur], Bs[cur], acc, wm, wn, r, q, xv);                     \
        __builtin_amdgcn_sched_barrier(0);                                      \
        __builtin_amdgcn_s_barrier();                                           \
        __builtin_amdgcn_sched_barrier(0);                                      \
        if (t + 2 < nt) {                                                       \
            stage_sw64((Ab) + (long)(t + 2) * 64, (K), (rmA), As[cur], tid);    \
            stage_sw64((Bb) + (long)(t + 2) * 64, (K), 127, Bs[cur], tid);      \
        }                                                                       \
    }

// ---- GEMM1: C[M,512] = bf16(leaky(A[M,K] @ Bt[512,K]^T + bias)), LDS-staged store ----
__global__ __launch_bounds__(256) void k_gemm_bf16(const unsigned short* __restrict__ A,
                                                   const unsigned short* __restrict__ Bt,
                                                   const float* __restrict__ bias,
                                                   unsigned short* __restrict__ C,
                                                   int M, int K) {
    __shared__ __align__(16) unsigned short As[2][128 * 64];   // 32 KB
    __shared__ __align__(16) unsigned short Bs[2][128 * 64];   // 32 KB
    __shared__ __align__(16) unsigned short Ep[32 * 128];      // epilogue staging, 8 KB
    const int tid  = threadIdx.x;
    const int lane = tid & 63, wave = tid >> 6;
    int m0, n0;
    if (!map_block(blockIdx.x, M, m0, n0)) return;
    const int r = lane & 15, q = lane >> 4;
    const int xv = r & 7;
    const int wm = (wave & 1) * 64, wn = (wave >> 1) * 64;
    const int band = wm >> 6;
    const int rmA = M - 1 - m0;
    const unsigned short* Ab = A + (long)m0 * K;
    const unsigned short* Bb = Bt + (long)n0 * K;

    floatx4 acc[4][4];
#pragma unroll
    for (int i = 0; i < 4; ++i)
#pragma unroll
        for (int j = 0; j < 4; ++j) acc[i][j] = (floatx4){0.f, 0.f, 0.f, 0.f};

    GEMM_KLOOP(Ab, Bb, K, rmA)

    // epilogue: per i-band, stage 32 rows x 128 cols bf16 in LDS, then 16B/lane stores
    float bv[4];
#pragma unroll
    for (int j = 0; j < 4; ++j) bv[j] = bias[n0 + wn + j * 16 + r];

#pragma unroll
    for (int i = 0; i < 4; ++i) {
#pragma unroll
        for (int j = 0; j < 4; ++j) {
#pragma unroll
            for (int t2 = 0; t2 < 4; ++t2) {
                float v = acc[i][j][t2] + bv[j];
                v = v > 0.f ? v : NEG_SLOPE * v;
                Ep[(band * 16 + q * 4 + t2) * 128 + wn + j * 16 + r] = f2bf(v);
            }
        }
        __syncthreads();
#pragma unroll
        for (int rr = 0; rr < 2; ++rr) {
            int c = rr * 256 + tid;
            int lrow = c >> 4, ccol = c & 15;
            int grow = m0 + (lrow >> 4) * 64 + i * 16 + (lrow & 15);
            if (grow < M) {
                short8 v = *(const short8*)(Ep + lrow * 128 + ccol * 8);
                *(short8*)(C + (long)grow * D_HID + n0 + ccol * 8) = v;
            }
        }
        __syncthreads();
    }
}

// ---- GEMM2 fused with head: out[row] += sum_col leaky(A@Bt^T + b2) * wout[col] ----
__global__ __launch_bounds__(256) void k_gemm2f(const unsigned short* __restrict__ A,
                                                const unsigned short* __restrict__ Bt,
                                                const float* __restrict__ bias,
                                                const float* __restrict__ wout,
                                                float* __restrict__ out,
                                                int M, int K) {
    __shared__ __align__(16) unsigned short As[2][128 * 64];
    __shared__ __align__(16) unsigned short Bs[2][128 * 64];
    const int tid  = threadIdx.x;
    const int lane = tid & 63, wave = tid >> 6;
    int m0, n0;
    if (!map_block(blockIdx.x, M, m0, n0)) return;
    const int r = lane & 15, q = lane >> 4;
    const int xv = r & 7;
    const int wm = (wave & 1) * 64, wn = (wave >> 1) * 64;
    const int rmA = M - 1 - m0;
    const unsigned short* Ab = A + (long)m0 * K;
    const unsigned short* Bb = Bt + (long)n0 * K;

    floatx4 acc[4][4];
#pragma unroll
    for (int i = 0; i < 4; ++i)
#pragma unroll
        for (int j = 0; j < 4; ++j) acc[i][j] = (floatx4){0.f, 0.f, 0.f, 0.f};

    GEMM_KLOOP(Ab, Bb, K, rmA)

    float bv[4], wv[4];
#pragma unroll
    for (int j = 0; j < 4; ++j) {
        int col = n0 + wn + j * 16 + r;
        bv[j] = bias[col];
        wv[j] = wout[col];
    }
#pragma unroll
    for (int i = 0; i < 4; ++i) {
#pragma unroll
        for (int t2 = 0; t2 < 4; ++t2) {
            float p = 0.f;
#pragma unroll
            for (int j = 0; j < 4; ++j) {
                float v = acc[i][j][t2] + bv[j];
                v = v > 0.f ? v : NEG_SLOPE * v;
                p += v * wv[j];
            }
            p += __shfl_xor(p, 8, 64);
            p += __shfl_xor(p, 4, 64);
            p += __shfl_xor(p, 2, 64);
            p += __shfl_xor(p, 1, 64);
            if (r == 0) {
                int row = m0 + wm + i * 16 + q * 4 + t2;
                if (row < M) atomicAdd(&out[row], p);   // out pre-seeded with b_out
            }
        }
    }
}

extern "C" void kernel_launch(void* const* d_in, const int* in_sizes, int n_in,
                              void* d_out, int out_size, void* d_ws, size_t ws_size,
                              hipStream_t stream) {
    const float* x     = (const float*)d_in[0];
    const void*  ei    = d_in[1];
    const float* W_gcn = (const float*)d_in[2];
    const float* b_gcn = (const float*)d_in[3];
    const float* W2    = (const float*)d_in[4];
    const float* b2    = (const float*)d_in[5];
    const float* W_out = (const float*)d_in[6];
    const float* b_out = (const float*)d_in[7];
    float* out = (float*)d_out;

    const int N = in_sizes[0] / D_IN;
    const int E = in_sizes[1] / 2;
    const int NB = (N + SCAN_CHUNK - 1) / SCAN_CHUNK;

    char* w = (char*)d_ws;
    size_t off = 0;
    auto alloc = [&](size_t bytes) { char* p = w + off; off = (off + bytes + 255) & ~(size_t)255; return p; };
    int*            flag   = (int*)alloc(256);
    float*          dinv   = (float*)alloc((size_t)N * 4);
    int*            deg_i  = (int*)alloc((size_t)N * 4);
    int*            offs   = (int*)alloc((size_t)(N + 1) * 4);
    int*            bsum   = (int*)alloc((size_t)NB * 4);
    int*            rank   = (int*)alloc((size_t)(E + 16) * 4);
    int*            esrc   = (int*)alloc((size_t)(E + 16) * 4);
    unsigned short* xb     = (unsigned short*)alloc((size_t)N * D_IN * 2);
    unsigned short* aggb   = (unsigned short*)alloc((size_t)N * D_IN * 2);
    unsigned short* h1     = (unsigned short*)alloc((size_t)N * D_HID * 2);
    unsigned short* Wgt    = (unsigned short*)alloc((size_t)D_IN * D_HID * 2);
    unsigned short* W2t    = (unsigned short*)alloc((size_t)D_HID * D_HID * 2);

    int npairs = E < 2048 ? E : 2048;
    long xthreads = (long)N * D_IN / 4;
    int init_blocks = 96 + (int)((xthreads + 255) / 256);
    k_init<<<init_blocks, 256, 0, stream>>>(x, xb, deg_i, N, (const unsigned int*)ei,
                                            npairs, flag, b_out, out,
                                            W_gcn, Wgt, W2, W2t, xthreads);

    k_deg_count<<<(E + 255) / 256, 256, 0, stream>>>(ei, flag, deg_i, rank, E);
    k_scan1<<<NB, 256, 0, stream>>>(deg_i, bsum, N);
    k_scan23<<<NB, 256, 0, stream>>>(deg_i, bsum, NB, offs, dinv, N);
    k_fill<<<(E + 255) / 256, 256, 0, stream>>>(ei, flag, offs, rank, esrc, E);

    k_gather<<<(N + 3) / 4, 256, 0, stream>>>(xb, offs, esrc, dinv, aggb, N);

    int mtiles = (N + 127) / 128;
    int gblocks = ((mtiles + 7) / 8) * 8 * 4;
    k_gemm_bf16<<<gblocks, 256, 0, stream>>>(aggb, Wgt, b_gcn, h1, N, D_IN);
    k_gemm2f<<<gblocks, 256, 0, stream>>>(h1, W2t, b2, W_out, out, N, D_HID);
}

// Round 8
// 281.205 us; speedup vs baseline: 1.2029x; 1.0368x over previous
//
#include <hip/hip_runtime.h>

#define D_IN  256
#define D_HID 512
#define NEG_SLOPE 0.2f
#define CAP 64                 // bucket slots per node; P(deg>64) ~ e^-42 at lambda=16
#define OVF_MAX 65536

typedef __attribute__((ext_vector_type(8))) short short8;
typedef __attribute__((ext_vector_type(4))) float floatx4;

__device__ __forceinline__ unsigned short f2bf(float f) {
    unsigned int u = __float_as_uint(f);
    u += 0x7fffu + ((u >> 16) & 1u);   // round-to-nearest-even
    return (unsigned short)(u >> 16);
}
__device__ __forceinline__ float bf2f(unsigned short u) {
    return __uint_as_float(((unsigned int)u) << 16);
}

__device__ __forceinline__ int eidx(const void* ei, long pos, int is64) {
    return is64 ? (int)((const long long*)ei)[pos] : ((const int*)ei)[pos];
}

// ---- init: blocks 0..95 LDS-tiled weight transposes; blocks 96.. convert x->bf16
//      (unscaled), zero deg, seed out=b_out; block 96 also detects edge dtype ----
__global__ __launch_bounds__(256) void k_init(const float* __restrict__ x,
                                              unsigned short* __restrict__ xb,
                                              int* __restrict__ deg, int N,
                                              const unsigned int* __restrict__ ei,
                                              int npairs, int* flag, int* ovfcnt,
                                              const float* __restrict__ b_out,
                                              float* __restrict__ out,
                                              const float* __restrict__ Wa,
                                              unsigned short* __restrict__ Wat,
                                              const float* __restrict__ Wb,
                                              unsigned short* __restrict__ Wbt,
                                              long xthreads) {
    __shared__ float tl[64][65];
    int b = blockIdx.x;
    if (b < 96) {                      // weight transpose, coalesced both ways
        const float* W; unsigned short* Wt; int K, Nc, tk, tn;
        if (b < 32) { W = Wa; Wt = Wat; K = 256; Nc = 512; tk = b & 3; tn = b >> 2; }
        else { b -= 32; W = Wb; Wt = Wbt; K = 512; Nc = 512; tk = b & 7; tn = b >> 3; }
        int k0 = tk * 64, n0 = tn * 64;
        int c = threadIdx.x & 63;
        int r0 = threadIdx.x >> 6;
#pragma unroll
        for (int i = 0; i < 16; ++i) {
            int r = r0 + i * 4;
            tl[r][c] = W[(long)(k0 + r) * Nc + n0 + c];
        }
        __syncthreads();
#pragma unroll
        for (int i = 0; i < 16; ++i) {
            int r = r0 + i * 4;
            Wt[(long)(n0 + r) * K + k0 + c] = f2bf(tl[c][r]);
        }
        return;
    }
    if (b == 96) {                     // dtype detect + overflow counter reset
        __shared__ int nz;
        if (threadIdx.x == 0) nz = 0;
        __syncthreads();
        for (int p = threadIdx.x; p < npairs; p += blockDim.x)
            if (ei[2 * p + 1] != 0) nz = 1;
        __syncthreads();
        if (threadIdx.x == 0) { *flag = nz ? 0 : 1; *ovfcnt = 0; }   // 1 => int64
    }
    long t = (long)(b - 96) * 256 + threadIdx.x;
    if (t < xthreads) {                // 1 thread = 4 floats
        long i = t * 4;
        float4 v = *(const float4*)(x + i);
        ushort4 o;
        o.x = f2bf(v.x); o.y = f2bf(v.y); o.z = f2bf(v.z); o.w = f2bf(v.w);
        *(ushort4*)(xb + i) = o;
    }
    if (t < N) { deg[t] = 0; out[t] = b_out[0]; }   // gemm2f atomically adds on top
}

// ---- degree count + DIRECT bucket fill: ONE edge pass builds the whole structure.
//      rank = atomicAdd(deg[dst]); esrc slot = dst*CAP + rank. No scan, no re-read.
//      Overflow (never happens at lambda=16, CAP=64) goes to a tiny global list. ----
__global__ void k_degfill(const void* __restrict__ ei, const int* __restrict__ flag,
                          int* __restrict__ deg, int* __restrict__ esrc,
                          int2* __restrict__ ovf, int* __restrict__ ovfcnt, int E) {
    int e = blockIdx.x * blockDim.x + threadIdx.x;
    if (e >= E) return;
    int is64 = *flag;
    int s = eidx(ei, e, is64), d = eidx(ei, (long)E + e, is64);
    int r = atomicAdd(&deg[d], 1);
    if (r < CAP) {
        esrc[d * CAP + r] = s;
    } else {
        int p = atomicAdd(ovfcnt, 1);
        if (p < OVF_MAX) ovf[p] = make_int2(d, s);
    }
}

// ---- dinv from final degree ----
__global__ __launch_bounds__(256) void k_dinv(const int* __restrict__ deg,
                                              float* __restrict__ dinv, int N) {
    int i = blockIdx.x * blockDim.x + threadIdx.x;
    if (i < N) dinv[i] = rsqrtf(1.0f + (float)deg[i]);
}

// ---- gather: wave=node, bucketed edge list (base node*CAP, count deg[node]) ----
__global__ __launch_bounds__(256) void k_gather(const unsigned short* __restrict__ xb,
                                                const int* __restrict__ deg,
                                                const int* __restrict__ esrc,
                                                const float* __restrict__ dinv,
                                                const int2* __restrict__ ovf,
                                                const int* __restrict__ ovfcnt,
                                                unsigned short* __restrict__ aggb, int N) {
    int node = blockIdx.x * 4 + (threadIdx.x >> 6);
    int lane = threadIdx.x & 63;
    if (node >= N) return;
    int half = lane >> 5;
    int li   = lane & 31;
    int colofs = li * 8;
    float di = dinv[node];

    float a[8];
    {
        short8 v = *(const short8*)(xb + (long)node * D_IN + colofs);
#pragma unroll
        for (int j = 0; j < 8; ++j)
            a[j] = (half == 0) ? di * bf2f((unsigned short)v[j]) : 0.f;
    }

    int cnt = deg[node];
    if (cnt > CAP) cnt = CAP;
    int beg = node * CAP, end = beg + cnt;
    int e = beg;
    for (; e + 8 <= end; e += 8) {      // 4 x 1KB wave-loads in flight
        int s0 = esrc[e + half];
        int s1 = esrc[e + 2 + half];
        int s2 = esrc[e + 4 + half];
        int s3 = esrc[e + 6 + half];
        float w0 = dinv[s0], w1 = dinv[s1], w2 = dinv[s2], w3 = dinv[s3];
        short8 u0 = *(const short8*)(xb + (long)s0 * D_IN + colofs);
        short8 u1 = *(const short8*)(xb + (long)s1 * D_IN + colofs);
        short8 u2 = *(const short8*)(xb + (long)s2 * D_IN + colofs);
        short8 u3 = *(const short8*)(xb + (long)s3 * D_IN + colofs);
#pragma unroll
        for (int j = 0; j < 8; ++j)
            a[j] += w0 * bf2f((unsigned short)u0[j]) + w1 * bf2f((unsigned short)u1[j])
                  + w2 * bf2f((unsigned short)u2[j]) + w3 * bf2f((unsigned short)u3[j]);
    }
    for (; e < end; e += 2) {
        int j0 = e + half;
        int jj = (j0 < end) ? j0 : end - 1;
        int s = esrc[jj];
        float w = (j0 < end) ? dinv[s] : 0.f;
        short8 u = *(const short8*)(xb + (long)s * D_IN + colofs);
#pragma unroll
        for (int j = 0; j < 8; ++j)
            a[j] += w * bf2f((unsigned short)u[j]);
    }

    // overflow edges (correctness path; empty in practice -> one scalar load)
    int oc = *ovfcnt;
    if (oc > OVF_MAX) oc = OVF_MAX;
    for (int i = 0; i < oc; ++i) {
        int2 p = ovf[i];
        if (p.x == node && half == 0) {
            float w = dinv[p.y];
            short8 u = *(const short8*)(xb + (long)p.y * D_IN + colofs);
#pragma unroll
            for (int j = 0; j < 8; ++j)
                a[j] += w * bf2f((unsigned short)u[j]);
        }
    }

#pragma unroll
    for (int j = 0; j < 8; ++j) a[j] += __shfl_xor(a[j], 32, 64);

    if (half == 0) {
        short8 o;
#pragma unroll
        for (int j = 0; j < 8; ++j) o[j] = (short)f2bf(a[j] * di);
        *(short8*)(aggb + (long)node * D_IN + colofs) = o;
    }
}

// ============ BK=64 swizzled-LDS 128x128 GEMM, counted-vmcnt 2-deep pipeline ======
__device__ __forceinline__ void async_cp16(const unsigned short* gp, unsigned short* lp) {
    __builtin_amdgcn_global_load_lds((const __attribute__((address_space(1))) void*)gp,
                                     (__attribute__((address_space(3))) void*)lp, 16, 0, 0);
}

__device__ __forceinline__ void stage_sw64(const unsigned short* src, int strideK,
                                           int rowMax, unsigned short* lds, int tid) {
#pragma unroll
    for (int rr = 0; rr < 4; ++rr) {
        int c = rr * 256 + tid;          // 0..1023 16B chunks
        int row = c >> 3;
        int ci = (c & 7) ^ (row & 7);    // logical chunk stored at this slot
        if (row > rowMax) row = rowMax;
        async_cp16(src + (long)row * strideK + ci * 8, lds + c * 8);
    }
}

__device__ __forceinline__ bool map_block(int b, int M, int& m0, int& n0) {
    int x = b & 7, slot = b >> 3;
    int mt = x + 8 * (slot >> 2);
    m0 = mt * 128; n0 = (slot & 3) * 128;
    return m0 < M;
}

__device__ __forceinline__ void mfma_step(const unsigned short* As_,
                                          const unsigned short* Bs_,
                                          floatx4 acc[4][4],
                                          int wm, int wn, int r, int q, int xv) {
#pragma unroll
    for (int s = 0; s < 2; ++s) {        // two K=32 sub-steps per tile
        int slotbase = s * 4 + q;
        short8 af[4], bf[4];
#pragma unroll
        for (int i = 0; i < 4; ++i)
            af[i] = *(const short8*)(As_ + (wm + i * 16 + r) * 64 + (slotbase ^ xv) * 8);
#pragma unroll
        for (int j = 0; j < 4; ++j)
            bf[j] = *(const short8*)(Bs_ + (wn + j * 16 + r) * 64 + (slotbase ^ xv) * 8);
#pragma unroll
        for (int i = 0; i < 4; ++i)
#pragma unroll
            for (int j = 0; j < 4; ++j)
                acc[i][j] = __builtin_amdgcn_mfma_f32_16x16x32_bf16(af[i], bf[j], acc[i][j], 0, 0, 0);
    }
}

// K-loop body shared by both GEMMs. 8 global_load_lds per thread per tile:
// vmcnt(8) == "my older tile has fully landed".
#define GEMM_KLOOP(Ab, Bb, K, rmA)                                              \
    const int nt = (K) >> 6;                                                    \
    stage_sw64((Ab), (K), (rmA), As[0], tid);                                   \
    stage_sw64((Bb), (K), 127, Bs[0], tid);                                     \
    if (nt > 1) {                                                               \
        stage_sw64((Ab) + 64, (K), (rmA), As[1], tid);                          \
        stage_sw64((Bb) + 64, (K), 127, Bs[1], tid);                            \
    }                                                                           \
    for (int t = 0; t < nt; ++t) {                                              \
        const int cur = t & 1;                                                  \
        if (t + 1 < nt) asm volatile("s_waitcnt vmcnt(8)" ::: "memory");        \
        else            asm volatile("s_waitcnt vmcnt(0)" ::: "memory");        \
        __builtin_amdgcn_sched_barrier(0);                                      \
        __builtin_amdgcn_s_barrier();                                           \
        __builtin_amdgcn_sched_barrier(0);                                      \
        mfma_step(As[cur], Bs[cur], acc, wm, wn, r, q, xv);                     \
        __builtin_amdgcn_sched_barrier(0);                                      \
        __builtin_amdgcn_s_barrier();                                           \
        __builtin_amdgcn_sched_barrier(0);                                      \
        if (t + 2 < nt) {                                                       \
            stage_sw64((Ab) + (long)(t + 2) * 64, (K), (rmA), As[cur], tid);    \
            stage_sw64((Bb) + (long)(t + 2) * 64, (K), 127, Bs[cur], tid);      \
        }                                                                       \
    }

// ---- GEMM1: C[M,512] = bf16(leaky(A[M,K] @ Bt[512,K]^T + bias)), LDS-staged store ----
__global__ __launch_bounds__(256) void k_gemm_bf16(const unsigned short* __restrict__ A,
                                                   const unsigned short* __restrict__ Bt,
                                                   const float* __restrict__ bias,
                                                   unsigned short* __restrict__ C,
                                                   int M, int K) {
    __shared__ __align__(16) unsigned short As[2][128 * 64];   // 32 KB
    __shared__ __align__(16) unsigned short Bs[2][128 * 64];   // 32 KB
    __shared__ __align__(16) unsigned short Ep[32 * 128];      // epilogue staging, 8 KB
    const int tid  = threadIdx.x;
    const int lane = tid & 63, wave = tid >> 6;
    int m0, n0;
    if (!map_block(blockIdx.x, M, m0, n0)) return;
    const int r = lane & 15, q = lane >> 4;
    const int xv = r & 7;
    const int wm = (wave & 1) * 64, wn = (wave >> 1) * 64;
    const int band = wm >> 6;
    const int rmA = M - 1 - m0;
    const unsigned short* Ab = A + (long)m0 * K;
    const unsigned short* Bb = Bt + (long)n0 * K;

    floatx4 acc[4][4];
#pragma unroll
    for (int i = 0; i < 4; ++i)
#pragma unroll
        for (int j = 0; j < 4; ++j) acc[i][j] = (floatx4){0.f, 0.f, 0.f, 0.f};

    GEMM_KLOOP(Ab, Bb, K, rmA)

    // epilogue: per i-band, stage 32 rows x 128 cols bf16 in LDS, then 16B/lane stores
    float bv[4];
#pragma unroll
    for (int j = 0; j < 4; ++j) bv[j] = bias[n0 + wn + j * 16 + r];

#pragma unroll
    for (int i = 0; i < 4; ++i) {
#pragma unroll
        for (int j = 0; j < 4; ++j) {
#pragma unroll
            for (int t2 = 0; t2 < 4; ++t2) {
                float v = acc[i][j][t2] + bv[j];
                v = v > 0.f ? v : NEG_SLOPE * v;
                Ep[(band * 16 + q * 4 + t2) * 128 + wn + j * 16 + r] = f2bf(v);
            }
        }
        __syncthreads();
#pragma unroll
        for (int rr = 0; rr < 2; ++rr) {
            int c = rr * 256 + tid;
            int lrow = c >> 4, ccol = c & 15;
            int grow = m0 + (lrow >> 4) * 64 + i * 16 + (lrow & 15);
            if (grow < M) {
                short8 v = *(const short8*)(Ep + lrow * 128 + ccol * 8);
                *(short8*)(C + (long)grow * D_HID + n0 + ccol * 8) = v;
            }
        }
        __syncthreads();
    }
}

// ---- GEMM2 fused with head: out[row] += sum_col leaky(A@Bt^T + b2) * wout[col] ----
__global__ __launch_bounds__(256) void k_gemm2f(const unsigned short* __restrict__ A,
                                                const unsigned short* __restrict__ Bt,
                                                const float* __restrict__ bias,
                                                const float* __restrict__ wout,
                                                float* __restrict__ out,
                                                int M, int K) {
    __shared__ __align__(16) unsigned short As[2][128 * 64];
    __shared__ __align__(16) unsigned short Bs[2][128 * 64];
    const int tid  = threadIdx.x;
    const int lane = tid & 63, wave = tid >> 6;
    int m0, n0;
    if (!map_block(blockIdx.x, M, m0, n0)) return;
    const int r = lane & 15, q = lane >> 4;
    const int xv = r & 7;
    const int wm = (wave & 1) * 64, wn = (wave >> 1) * 64;
    const int rmA = M - 1 - m0;
    const unsigned short* Ab = A + (long)m0 * K;
    const unsigned short* Bb = Bt + (long)n0 * K;

    floatx4 acc[4][4];
#pragma unroll
    for (int i = 0; i < 4; ++i)
#pragma unroll
        for (int j = 0; j < 4; ++j) acc[i][j] = (floatx4){0.f, 0.f, 0.f, 0.f};

    GEMM_KLOOP(Ab, Bb, K, rmA)

    float bv[4], wv[4];
#pragma unroll
    for (int j = 0; j < 4; ++j) {
        int col = n0 + wn + j * 16 + r;
        bv[j] = bias[col];
        wv[j] = wout[col];
    }
#pragma unroll
    for (int i = 0; i < 4; ++i) {
#pragma unroll
        for (int t2 = 0; t2 < 4; ++t2) {
            float p = 0.f;
#pragma unroll
            for (int j = 0; j < 4; ++j) {
                float v = acc[i][j][t2] + bv[j];
                v = v > 0.f ? v : NEG_SLOPE * v;
                p += v * wv[j];
            }
            p += __shfl_xor(p, 8, 64);
            p += __shfl_xor(p, 4, 64);
            p += __shfl_xor(p, 2, 64);
            p += __shfl_xor(p, 1, 64);
            if (r == 0) {
                int row = m0 + wm + i * 16 + q * 4 + t2;
                if (row < M) atomicAdd(&out[row], p);   // out pre-seeded with b_out
            }
        }
    }
}

extern "C" void kernel_launch(void* const* d_in, const int* in_sizes, int n_in,
                              void* d_out, int out_size, void* d_ws, size_t ws_size,
                              hipStream_t stream) {
    const float* x     = (const float*)d_in[0];
    const void*  ei    = d_in[1];
    const float* W_gcn = (const float*)d_in[2];
    const float* b_gcn = (const float*)d_in[3];
    const float* W2    = (const float*)d_in[4];
    const float* b2    = (const float*)d_in[5];
    const float* W_out = (const float*)d_in[6];
    const float* b_out = (const float*)d_in[7];
    float* out = (float*)d_out;

    const int N = in_sizes[0] / D_IN;
    const int E = in_sizes[1] / 2;

    char* w = (char*)d_ws;
    size_t off = 0;
    auto alloc = [&](size_t bytes) { char* p = w + off; off = (off + bytes + 255) & ~(size_t)255; return p; };
    int*            flag   = (int*)alloc(256);
    int*            ovfcnt = (int*)alloc(256);
    float*          dinv   = (float*)alloc((size_t)N * 4);
    int*            deg_i  = (int*)alloc((size_t)N * 4);
    int2*           ovf    = (int2*)alloc((size_t)OVF_MAX * 8);
    int*            esrc   = (int*)alloc((size_t)N * CAP * 4);
    unsigned short* xb     = (unsigned short*)alloc((size_t)N * D_IN * 2);
    unsigned short* aggb   = (unsigned short*)alloc((size_t)N * D_IN * 2);
    unsigned short* h1     = (unsigned short*)alloc((size_t)N * D_HID * 2);
    unsigned short* Wgt    = (unsigned short*)alloc((size_t)D_IN * D_HID * 2);
    unsigned short* W2t    = (unsigned short*)alloc((size_t)D_HID * D_HID * 2);

    int npairs = E < 2048 ? E : 2048;
    long xthreads = (long)N * D_IN / 4;
    int init_blocks = 96 + (int)((xthreads + 255) / 256);
    k_init<<<init_blocks, 256, 0, stream>>>(x, xb, deg_i, N, (const unsigned int*)ei,
                                            npairs, flag, ovfcnt, b_out, out,
                                            W_gcn, Wgt, W2, W2t, xthreads);

    k_degfill<<<(E + 255) / 256, 256, 0, stream>>>(ei, flag, deg_i, esrc, ovf, ovfcnt, E);
    k_dinv<<<(N + 255) / 256, 256, 0, stream>>>(deg_i, dinv, N);

    k_gather<<<(N + 3) / 4, 256, 0, stream>>>(xb, deg_i, esrc, dinv, ovf, ovfcnt, aggb, N);

    int mtiles = (N + 127) / 128;
    int gblocks = ((mtiles + 7) / 8) * 8 * 4;
    k_gemm_bf16<<<gblocks, 256, 0, stream>>>(aggb, Wgt, b_gcn, h1, N, D_IN);
    k_gemm2f<<<gblocks, 256, 0, stream>>>(h1, W2t, b2, W_out, out, N, D_HID);
}